// Round 1
// baseline (2184.860 us; speedup 1.0000x reference)
//
#include <hip/hip_runtime.h>
#include <math.h>

#define NTOT 32768
#define HDIM 128
#define NE   524288
#define NGRAPH 32
#define NNODE 1024
#define NHEAD 4
#define DHEAD 32

typedef float f32;

__device__ __forceinline__ float4 ld4(const float* p){ return *(const float4*)p; }

// ---------------- CSR build ----------------
__global__ void k_count(const int* __restrict__ dst, int* __restrict__ deg){
  int e = blockIdx.x*256 + threadIdx.x;
  atomicAdd(&deg[dst[e]], 1);
}

__global__ __launch_bounds__(1024) void k_scan(const int* __restrict__ deg,
                                               int* __restrict__ indptr,
                                               int* __restrict__ cursor){
  __shared__ int sm[1024];
  int t = threadIdx.x;
  int base = t*32;
  int s = 0;
  for (int j=0;j<32;j++) s += deg[base+j];
  sm[t] = s; __syncthreads();
  for (int off=1; off<1024; off<<=1){
    int v = (t>=off) ? sm[t-off] : 0;
    __syncthreads();
    sm[t] += v;
    __syncthreads();
  }
  int ex = sm[t] - s;
  for (int j=0;j<32;j++){
    int d = deg[base+j];
    indptr[base+j] = ex; cursor[base+j] = ex;
    ex += d;
  }
  if (t == 1023) indptr[NTOT] = ex;
}

__global__ void k_fill(const int* __restrict__ dst, int* __restrict__ cursor,
                       int* __restrict__ perm){
  int e = blockIdx.x*256 + threadIdx.x;
  int pos = atomicAdd(&cursor[dst[e]], 1);
  perm[pos] = e;
}

// aggr[n][f] = sum over incoming edges of relu(x[src][f] + ea[e][f])
__global__ __launch_bounds__(128) void k_aggr(const float* __restrict__ x,
                       const float* __restrict__ ea,
                       const int* __restrict__ src, const int* __restrict__ indptr,
                       const int* __restrict__ perm, float* __restrict__ aggr){
  int n = blockIdx.x, f = threadIdx.x;
  int p0 = indptr[n], p1 = indptr[n+1];
  float acc = 0.f;
  for (int p=p0;p<p1;p++){
    int e = perm[p];
    int sidx = src[e];
    float v = x[(size_t)sidx*HDIM + f] + ea[(size_t)e*HDIM + f];
    acc += fmaxf(v, 0.f);
  }
  aggr[(size_t)n*HDIM + f] = acc;
}

// ---------------- GEMM: C[M,N] = act( (A (+A2)) @ W^T + bias (+Ep) ) ----------------
// BM=128, BN=64, BK=32, 256 threads, 8x4 per-thread tile
template<bool ADDA, bool RELU, bool EP>
__global__ __launch_bounds__(256) void k_gemm(const float* __restrict__ A,
    const float* __restrict__ A2, const float* __restrict__ W,
    const float* __restrict__ bias, const float* __restrict__ Ep,
    float* __restrict__ C, int N, int K){
  __shared__ float As[32][132];   // [k][m], pad 4 keeps b128 reads conflict-free
  __shared__ float Ws[32][68];    // [k][n]
  int tid = threadIdx.x;
  int tx = tid & 15, ty = tid >> 4;
  int m0 = blockIdx.x * 128, n0 = blockIdx.y * 64;
  float acc[8][4];
  #pragma unroll
  for (int i=0;i<8;i++)
    #pragma unroll
    for (int j=0;j<4;j++) acc[i][j]=0.f;
  int lr = tid >> 3;          // 0..31
  int lc = (tid & 7) << 2;    // 0,4,...,28
  for (int kc=0; kc<K; kc+=32){
    #pragma unroll
    for (int p=0;p<4;p++){
      int rr = lr + 32*p;
      float4 v = ld4(&A[(size_t)(m0+rr)*K + kc + lc]);
      if (ADDA){
        float4 u = ld4(&A2[(size_t)(m0+rr)*K + kc + lc]);
        v.x+=u.x; v.y+=u.y; v.z+=u.z; v.w+=u.w;
      }
      As[lc+0][rr]=v.x; As[lc+1][rr]=v.y; As[lc+2][rr]=v.z; As[lc+3][rr]=v.w;
    }
    #pragma unroll
    for (int p=0;p<2;p++){
      int rr = lr + 32*p;
      float4 v = ld4(&W[(size_t)(n0+rr)*K + kc + lc]);
      Ws[lc+0][rr]=v.x; Ws[lc+1][rr]=v.y; Ws[lc+2][rr]=v.z; Ws[lc+3][rr]=v.w;
    }
    __syncthreads();
    #pragma unroll
    for (int k=0;k<32;k++){
      float4 a0 = *(const float4*)&As[k][ty*8];
      float4 a1 = *(const float4*)&As[k][ty*8+4];
      float4 b  = *(const float4*)&Ws[k][tx*4];
      float av[8] = {a0.x,a0.y,a0.z,a0.w,a1.x,a1.y,a1.z,a1.w};
      float bv[4] = {b.x,b.y,b.z,b.w};
      #pragma unroll
      for (int i=0;i<8;i++)
        #pragma unroll
        for (int j=0;j<4;j++) acc[i][j] = fmaf(av[i], bv[j], acc[i][j]);
    }
    __syncthreads();
  }
  float4 bj = ld4(&bias[n0 + tx*4]);
  float bb[4] = {bj.x,bj.y,bj.z,bj.w};
  #pragma unroll
  for (int i=0;i<8;i++){
    int row = m0 + ty*8 + i;
    float vals[4];
    #pragma unroll
    for (int j=0;j<4;j++) vals[j] = acc[i][j] + bb[j];
    if (EP){
      float4 e = ld4(&Ep[(size_t)row*N + n0 + tx*4]);
      vals[0]+=e.x; vals[1]+=e.y; vals[2]+=e.z; vals[3]+=e.w;
    }
    if (RELU){
      #pragma unroll
      for (int j=0;j<4;j++) vals[j] = fmaxf(vals[j],0.f);
    }
    float4 o = make_float4(vals[0],vals[1],vals[2],vals[3]);
    *(float4*)&C[(size_t)row*N + n0 + tx*4] = o;
  }
}

// ---------------- BatchNorm ----------------
__global__ __launch_bounds__(128) void k_bnstats(const float* __restrict__ X, float* __restrict__ stats){
  int f = threadIdx.x;
  size_t r0 = (size_t)blockIdx.x*128;
  float s=0.f, q=0.f;
  for (int r=0;r<128;r++){
    float v = X[(r0+r)*HDIM + f];
    s += v; q += v*v;
  }
  atomicAdd(&stats[f], s);
  atomicAdd(&stats[128+f], q);
}

__global__ __launch_bounds__(128) void k_bnfinal(const float* __restrict__ g, const float* __restrict__ b,
                                                 float* __restrict__ stats){
  int f = threadIdx.x;
  const float invn = 1.0f/32768.0f;
  float mean = stats[f]*invn;
  float var  = stats[128+f]*invn - mean*mean;
  float sc = g[f] * rsqrtf(var + 1e-5f);
  stats[256+f] = sc;
  stats[384+f] = b[f] - mean*sc;
}

template<bool RELU>
__global__ __launch_bounds__(256) void k_bnapply(const float* __restrict__ X,
                                                 const float* __restrict__ stats,
                                                 float* __restrict__ Y){
  size_t i = (size_t)blockIdx.x*256 + threadIdx.x;
  int c = (int)(i & 31) * 4;
  float4 v = ((const float4*)X)[i];
  float4 sc = *(const float4*)&stats[256+c];
  float4 sh = *(const float4*)&stats[384+c];
  float4 y;
  y.x = v.x*sc.x + sh.x; y.y = v.y*sc.y + sh.y;
  y.z = v.z*sc.z + sh.z; y.w = v.w*sc.w + sh.w;
  if (RELU){
    y.x=fmaxf(y.x,0.f); y.y=fmaxf(y.y,0.f); y.z=fmaxf(y.z,0.f); y.w=fmaxf(y.w,0.f);
  }
  ((float4*)Y)[i] = y;
}

__global__ __launch_bounds__(256) void k_add(const float* __restrict__ A, const float* __restrict__ B,
                                             float* __restrict__ C){
  size_t i = (size_t)blockIdx.x*256 + threadIdx.x;
  float4 a = ((const float4*)A)[i];
  float4 b = ((const float4*)B)[i];
  float4 c; c.x=a.x+b.x; c.y=a.y+b.y; c.z=a.z+b.z; c.w=a.w+b.w;
  ((float4*)C)[i] = c;
}

// ---------------- Flash attention (fp32), per (qtile, head, graph) ----------------
__global__ __launch_bounds__(256) void k_flash(const float* __restrict__ qkv, float* __restrict__ O){
  const int qt = blockIdx.x, h = blockIdx.y, g = blockIdx.z;
  __shared__ float Qt[32][68];   // [d][qrow]
  __shared__ float Kt[32][68];   // [d][kcol], column-group XOR swizzled by (d>>1)&7
  __shared__ float Vt[32][68];   // same layout as Kt
  __shared__ float Pt[64][68];   // [kcol][qrow]
  int tid = threadIdx.x;
  int sx = tid & 15, sy = tid >> 4;   // sy: 16 groups of 4 q rows; sx: 16 groups of 4 k cols / 2 dims
  const float qscale = 0.17677669529663687f; // 1/sqrt(32)
  int lr = tid >> 3;          // 0..31
  int lc = (tid & 7) << 2;    // 0..28
  size_t grow0 = (size_t)g*NNODE;

  #pragma unroll
  for (int p=0;p<2;p++){
    int r = lr + 32*p;
    float4 v = ld4(&qkv[(grow0 + qt*64 + r)*384 + h*32 + lc]);
    Qt[lc+0][r]=v.x*qscale; Qt[lc+1][r]=v.y*qscale;
    Qt[lc+2][r]=v.z*qscale; Qt[lc+3][r]=v.w*qscale;
  }
  float m[4], l[4], o[4][2];
  #pragma unroll
  for (int i=0;i<4;i++){ m[i]=-INFINITY; l[i]=0.f; o[i][0]=0.f; o[i][1]=0.f; }

  for (int kt=0; kt<16; kt++){
    // stage K,V transposed + swizzled
    #pragma unroll
    for (int p=0;p<2;p++){
      int r = lr + 32*p;  // k index within tile
      const float* basek = &qkv[(grow0 + kt*64 + r)*384 + 128 + h*32 + lc];
      const float* basev = &qkv[(grow0 + kt*64 + r)*384 + 256 + h*32 + lc];
      float4 kv = ld4(basek);
      float4 vv = ld4(basev);
      float kk[4]={kv.x,kv.y,kv.z,kv.w};
      float vvv[4]={vv.x,vv.y,vv.z,vv.w};
      #pragma unroll
      for (int j=0;j<4;j++){
        int d = lc + j;
        int grp = (r>>2) ^ ((d>>1)&7);
        int colp = (r&3) + (grp<<2);
        Kt[d][colp] = kk[j];
        Vt[d][colp] = vvv[j];
      }
    }
    __syncthreads();
    // QK^T for 4 rows x 4 cols
    float s[4][4];
    #pragma unroll
    for (int i=0;i<4;i++)
      #pragma unroll
      for (int j=0;j<4;j++) s[i][j]=0.f;
    #pragma unroll
    for (int d0=0; d0<32; d0+=4){
      #pragma unroll
      for (int dd=0; dd<4; dd++){
        int d = d0+dd;
        float4 qv = *(const float4*)&Qt[d][sy*4];
        int grp = sx ^ ((d>>1)&7);
        float4 kv = *(const float4*)&Kt[d][grp<<2];
        float qq[4]={qv.x,qv.y,qv.z,qv.w};
        float kk[4]={kv.x,kv.y,kv.z,kv.w};
        #pragma unroll
        for (int i=0;i<4;i++)
          #pragma unroll
          for (int j=0;j<4;j++) s[i][j] = fmaf(qq[i], kk[j], s[i][j]);
      }
    }
    // online softmax per row (reduce across the 16 sx lanes)
    #pragma unroll
    for (int i=0;i<4;i++){
      float mx = fmaxf(fmaxf(s[i][0],s[i][1]), fmaxf(s[i][2],s[i][3]));
      mx = fmaxf(mx, __shfl_xor(mx,1));
      mx = fmaxf(mx, __shfl_xor(mx,2));
      mx = fmaxf(mx, __shfl_xor(mx,4));
      mx = fmaxf(mx, __shfl_xor(mx,8));
      float mn = fmaxf(m[i], mx);
      float al = __expf(m[i]-mn);
      float ps = 0.f;
      #pragma unroll
      for (int j=0;j<4;j++){ s[i][j] = __expf(s[i][j]-mn); ps += s[i][j]; }
      ps += __shfl_xor(ps,1); ps += __shfl_xor(ps,2);
      ps += __shfl_xor(ps,4); ps += __shfl_xor(ps,8);
      l[i] = l[i]*al + ps;
      m[i] = mn;
      o[i][0]*=al; o[i][1]*=al;
    }
    // write P transposed: Pt[kcol][qrow]
    #pragma unroll
    for (int j=0;j<4;j++){
      float4 pv = make_float4(s[0][j], s[1][j], s[2][j], s[3][j]);
      *(float4*)&Pt[sx*4+j][sy*4] = pv;
    }
    __syncthreads();
    // PV: o[4 rows][2 dims], dims d = 2*sx+dd
    #pragma unroll
    for (int j0=0;j0<64;j0+=4){
      int js = j0>>2;
      float4 pv[4];
      #pragma unroll
      for (int jj=0;jj<4;jj++) pv[jj] = *(const float4*)&Pt[j0+jj][sy*4];
      #pragma unroll
      for (int dd=0;dd<2;dd++){
        int d = sx*2+dd;
        int grp = js ^ ((d>>1)&7);
        float4 vv = *(const float4*)&Vt[d][grp<<2];
        float vvv[4]={vv.x,vv.y,vv.z,vv.w};
        #pragma unroll
        for (int jj=0;jj<4;jj++){
          o[0][dd] = fmaf(pv[jj].x, vvv[jj], o[0][dd]);
          o[1][dd] = fmaf(pv[jj].y, vvv[jj], o[1][dd]);
          o[2][dd] = fmaf(pv[jj].z, vvv[jj], o[2][dd]);
          o[3][dd] = fmaf(pv[jj].w, vvv[jj], o[3][dd]);
        }
      }
    }
    __syncthreads();
  }
  #pragma unroll
  for (int i=0;i<4;i++){
    float inv = 1.0f/l[i];
    size_t row = grow0 + qt*64 + sy*4 + i;
    O[row*HDIM + h*32 + sx*2 + 0] = o[i][0]*inv;
    O[row*HDIM + h*32 + sx*2 + 1] = o[i][1]*inv;
  }
}

// ---------------- host ----------------
extern "C" void kernel_launch(void* const* d_in, const int* in_sizes, int n_in,
                              void* d_out, int out_size, void* d_ws, size_t ws_size,
                              hipStream_t stream){
  const float* x_in      = (const float*)d_in[0];
  const float* edge_attr = (const float*)d_in[1];
  const float* gine_w1   = (const float*)d_in[2];
  const float* gine_b1   = (const float*)d_in[3];
  const float* gine_bn_g = (const float*)d_in[4];
  const float* gine_bn_b = (const float*)d_in[5];
  const float* gine_w2   = (const float*)d_in[6];
  const float* gine_b2   = (const float*)d_in[7];
  const float* attn_wqkv = (const float*)d_in[8];
  const float* attn_bqkv = (const float*)d_in[9];
  const float* attn_wo   = (const float*)d_in[10];
  const float* attn_bo   = (const float*)d_in[11];
  const float* norm1_g   = (const float*)d_in[12];
  const float* norm1_b   = (const float*)d_in[13];
  const float* norm2_g   = (const float*)d_in[14];
  const float* norm2_b   = (const float*)d_in[15];
  const float* norm3_g   = (const float*)d_in[16];
  const float* norm3_b   = (const float*)d_in[17];
  const float* mlp_w1    = (const float*)d_in[18];
  const float* mlp_b1    = (const float*)d_in[19];
  const float* mlp_w2    = (const float*)d_in[20];
  const float* mlp_b2    = (const float*)d_in[21];
  const int* edge_index  = (const int*)d_in[22];
  const int* srcp = edge_index;
  const int* dstp = edge_index + NE;
  float* out = (float*)d_out;

  float* ws = (float*)d_ws;
  const size_t U = 4194304; // NTOT*HDIM
  float* X     = ws;
  float* AGGR  = ws + 1*U;
  float* H1    = ws + 2*U;
  float* HATTN = ws + 3*U;
  float* OBUF  = ws + 4*U;
  float* FF    = ws + 5*U;   // 2 units (NTOT x 256)
  float* QKV   = ws + 7*U;   // 3 units (NTOT x 384)
  float* STATS = ws + 10*U;  // 512 floats
  int* IW      = (int*)(STATS + 512);
  int* deg     = IW;
  int* indptr  = IW + 32768;
  int* cursor  = IW + 32768 + 32772;
  int* perm    = cursor + 32768;

  // --- CSR build (same every layer) ---
  hipMemsetAsync(deg, 0, NTOT*sizeof(int), stream);
  k_count<<<NE/256, 256, 0, stream>>>(dstp, deg);
  k_scan<<<1, 1024, 0, stream>>>(deg, indptr, cursor);
  k_fill<<<NE/256, 256, 0, stream>>>(dstp, cursor, perm);
  hipMemcpyAsync(X, x_in, (size_t)NTOT*HDIM*sizeof(float), hipMemcpyDeviceToDevice, stream);

  const int GAPPLY = (NTOT*HDIM/4)/256; // 4096
  dim3 g128(NTOT/128, 2), g256(NTOT/128, 4), g384(NTOT/128, 6);
  dim3 gflash(16, NHEAD, NGRAPH);

  auto bn = [&](const float* data, const float* gg, const float* bb, float* dest, bool relu){
    hipMemsetAsync(STATS, 0, 256*sizeof(float), stream);
    k_bnstats<<<256, 128, 0, stream>>>(data, STATS);
    k_bnfinal<<<1, 128, 0, stream>>>(gg, bb, STATS);
    if (relu) k_bnapply<true ><<<GAPPLY, 256, 0, stream>>>(data, STATS, dest);
    else      k_bnapply<false><<<GAPPLY, 256, 0, stream>>>(data, STATS, dest);
  };

  for (int i=0;i<3;i++){
    const float* W1 = gine_w1 + (size_t)i*HDIM*HDIM;
    const float* B1 = gine_b1 + (size_t)i*HDIM;
    const float* W2 = gine_w2 + (size_t)i*HDIM*HDIM;
    const float* B2 = gine_b2 + (size_t)i*HDIM;
    const float* WQ = attn_wqkv + (size_t)i*3*HDIM*HDIM;
    const float* BQ = attn_bqkv + (size_t)i*3*HDIM;
    const float* WO = attn_wo + (size_t)i*HDIM*HDIM;
    const float* BO = attn_bo + (size_t)i*HDIM;
    const float* WM1 = mlp_w1 + (size_t)i*2*HDIM*HDIM;
    const float* BM1 = mlp_b1 + (size_t)i*2*HDIM;
    const float* WM2 = mlp_w2 + (size_t)i*2*HDIM*HDIM;
    const float* BM2 = mlp_b2 + (size_t)i*HDIM;

    // GINE
    k_aggr<<<NTOT, 128, 0, stream>>>(X, edge_attr, srcp, indptr, perm, AGGR);
    k_gemm<true,false,false><<<g128, 256, 0, stream>>>(X, AGGR, W1, B1, nullptr, H1, 128, 128);
    bn(H1, gine_bn_g + (size_t)i*HDIM, gine_bn_b + (size_t)i*HDIM, H1, true);
    k_gemm<false,false,true><<<g128, 256, 0, stream>>>(H1, nullptr, W2, B2, X, AGGR, 128, 128);
    bn(AGGR, norm1_g + (size_t)i*HDIM, norm1_b + (size_t)i*HDIM, H1, false); // h_local -> H1

    // attention
    k_gemm<false,false,false><<<g384, 256, 0, stream>>>(X, nullptr, WQ, BQ, nullptr, QKV, 384, 128);
    k_flash<<<gflash, 256, 0, stream>>>(QKV, OBUF);
    k_gemm<false,false,true><<<g128, 256, 0, stream>>>(OBUF, nullptr, WO, BO, X, AGGR, 128, 128);
    bn(AGGR, norm2_g + (size_t)i*HDIM, norm2_b + (size_t)i*HDIM, HATTN, false); // h_attn -> HATTN

    // combine + FFN
    k_add<<<GAPPLY, 256, 0, stream>>>(H1, HATTN, AGGR);  // out -> AGGR
    k_gemm<false,true,false><<<g256, 256, 0, stream>>>(AGGR, nullptr, WM1, BM1, nullptr, FF, 256, 128);
    k_gemm<false,false,true><<<g128, 256, 0, stream>>>(FF, nullptr, WM2, BM2, AGGR, HATTN, 128, 256);
    float* dest = (i==2) ? out : X;
    bn(HATTN, norm3_g + (size_t)i*HDIM, norm3_b + (size_t)i*HDIM, dest, i<2);
  }
}

// Round 2
// 1560.644 us; speedup vs baseline: 1.4000x; 1.4000x over previous
//
#include <hip/hip_runtime.h>
#include <hip/hip_bf16.h>
#include <math.h>

#define NTOT 32768
#define HDIM 128
#define NE   524288
#define NGRAPH 32
#define NNODE 1024
#define NHEAD 4
#define DHEAD 32

typedef __attribute__((ext_vector_type(8))) short bf8v;
typedef __attribute__((ext_vector_type(4))) float f4v;

__device__ __forceinline__ float4 ld4(const float* p){ return *(const float4*)p; }

__device__ __forceinline__ unsigned short bf16rn(float f){
  union { float f; unsigned u; } x; x.f = f;
  unsigned r = x.u + 0x7FFF + ((x.u >> 16) & 1);
  return (unsigned short)(r >> 16);
}

// ---------------- CSR build ----------------
__global__ void k_count(const int* __restrict__ dst, int* __restrict__ deg){
  int e = blockIdx.x*256 + threadIdx.x;
  atomicAdd(&deg[dst[e]], 1);
}

__global__ __launch_bounds__(1024) void k_scan(const int* __restrict__ deg,
                                               int* __restrict__ indptr,
                                               int* __restrict__ cursor){
  __shared__ int sm[1024];
  int t = threadIdx.x;
  int base = t*32;
  int s = 0;
  for (int j=0;j<32;j++) s += deg[base+j];
  sm[t] = s; __syncthreads();
  for (int off=1; off<1024; off<<=1){
    int v = (t>=off) ? sm[t-off] : 0;
    __syncthreads();
    sm[t] += v;
    __syncthreads();
  }
  int ex = sm[t] - s;
  for (int j=0;j<32;j++){
    int d = deg[base+j];
    indptr[base+j] = ex; cursor[base+j] = ex;
    ex += d;
  }
  if (t == 1023) indptr[NTOT] = ex;
}

__global__ void k_fill(const int* __restrict__ dst, int* __restrict__ cursor,
                       int* __restrict__ perm){
  int e = blockIdx.x*256 + threadIdx.x;
  int pos = atomicAdd(&cursor[dst[e]], 1);
  perm[pos] = e;
}

// aggr[n][f] = sum over incoming edges of relu(x[src][f] + ea[e][f])
__global__ __launch_bounds__(128) void k_aggr(const float* __restrict__ x,
                       const float* __restrict__ ea,
                       const int* __restrict__ src, const int* __restrict__ indptr,
                       const int* __restrict__ perm, float* __restrict__ aggr){
  int n = blockIdx.x, f = threadIdx.x;
  int p0 = indptr[n], p1 = indptr[n+1];
  float acc = 0.f;
  for (int p=p0;p<p1;p++){
    int e = perm[p];
    int sidx = src[e];
    float v = x[(size_t)sidx*HDIM + f] + ea[(size_t)e*HDIM + f];
    acc += fmaxf(v, 0.f);
  }
  aggr[(size_t)n*HDIM + f] = acc;
}

// ---------------- GEMM: C[M,N] = act( (A (+A2)) @ W^T + bias (+Ep) ) ----------------
template<bool ADDA, bool RELU, bool EP>
__global__ __launch_bounds__(256) void k_gemm(const float* __restrict__ A,
    const float* __restrict__ A2, const float* __restrict__ W,
    const float* __restrict__ bias, const float* __restrict__ Ep,
    float* __restrict__ C, int N, int K){
  __shared__ float As[32][132];
  __shared__ float Ws[32][68];
  int tid = threadIdx.x;
  int tx = tid & 15, ty = tid >> 4;
  int m0 = blockIdx.x * 128, n0 = blockIdx.y * 64;
  float acc[8][4];
  #pragma unroll
  for (int i=0;i<8;i++)
    #pragma unroll
    for (int j=0;j<4;j++) acc[i][j]=0.f;
  int lr = tid >> 3;
  int lc = (tid & 7) << 2;
  for (int kc=0; kc<K; kc+=32){
    #pragma unroll
    for (int p=0;p<4;p++){
      int rr = lr + 32*p;
      float4 v = ld4(&A[(size_t)(m0+rr)*K + kc + lc]);
      if (ADDA){
        float4 u = ld4(&A2[(size_t)(m0+rr)*K + kc + lc]);
        v.x+=u.x; v.y+=u.y; v.z+=u.z; v.w+=u.w;
      }
      As[lc+0][rr]=v.x; As[lc+1][rr]=v.y; As[lc+2][rr]=v.z; As[lc+3][rr]=v.w;
    }
    #pragma unroll
    for (int p=0;p<2;p++){
      int rr = lr + 32*p;
      float4 v = ld4(&W[(size_t)(n0+rr)*K + kc + lc]);
      Ws[lc+0][rr]=v.x; Ws[lc+1][rr]=v.y; Ws[lc+2][rr]=v.z; Ws[lc+3][rr]=v.w;
    }
    __syncthreads();
    #pragma unroll
    for (int k=0;k<32;k++){
      float4 a0 = *(const float4*)&As[k][ty*8];
      float4 a1 = *(const float4*)&As[k][ty*8+4];
      float4 b  = *(const float4*)&Ws[k][tx*4];
      float av[8] = {a0.x,a0.y,a0.z,a0.w,a1.x,a1.y,a1.z,a1.w};
      float bv[4] = {b.x,b.y,b.z,b.w};
      #pragma unroll
      for (int i=0;i<8;i++)
        #pragma unroll
        for (int j=0;j<4;j++) acc[i][j] = fmaf(av[i], bv[j], acc[i][j]);
    }
    __syncthreads();
  }
  float4 bj = ld4(&bias[n0 + tx*4]);
  float bb[4] = {bj.x,bj.y,bj.z,bj.w};
  #pragma unroll
  for (int i=0;i<8;i++){
    int row = m0 + ty*8 + i;
    float vals[4];
    #pragma unroll
    for (int j=0;j<4;j++) vals[j] = acc[i][j] + bb[j];
    if (EP){
      float4 e = ld4(&Ep[(size_t)row*N + n0 + tx*4]);
      vals[0]+=e.x; vals[1]+=e.y; vals[2]+=e.z; vals[3]+=e.w;
    }
    if (RELU){
      #pragma unroll
      for (int j=0;j<4;j++) vals[j] = fmaxf(vals[j],0.f);
    }
    float4 o = make_float4(vals[0],vals[1],vals[2],vals[3]);
    *(float4*)&C[(size_t)row*N + n0 + tx*4] = o;
  }
}

// ---------------- BatchNorm ----------------
__global__ __launch_bounds__(128) void k_bnstats(const float* __restrict__ X, float* __restrict__ stats){
  int f = threadIdx.x;
  size_t r0 = (size_t)blockIdx.x*128;
  float s=0.f, q=0.f;
  for (int r=0;r<128;r++){
    float v = X[(r0+r)*HDIM + f];
    s += v; q += v*v;
  }
  atomicAdd(&stats[f], s);
  atomicAdd(&stats[128+f], q);
}

__global__ __launch_bounds__(128) void k_bnfinal(const float* __restrict__ g, const float* __restrict__ b,
                                                 float* __restrict__ stats){
  int f = threadIdx.x;
  const float invn = 1.0f/32768.0f;
  float mean = stats[f]*invn;
  float var  = stats[128+f]*invn - mean*mean;
  float sc = g[f] * rsqrtf(var + 1e-5f);
  stats[256+f] = sc;
  stats[384+f] = b[f] - mean*sc;
}

template<bool RELU>
__global__ __launch_bounds__(256) void k_bnapply(const float* __restrict__ X,
                                                 const float* __restrict__ stats,
                                                 float* __restrict__ Y){
  size_t i = (size_t)blockIdx.x*256 + threadIdx.x;
  int c = (int)(i & 31) * 4;
  float4 v = ((const float4*)X)[i];
  float4 sc = *(const float4*)&stats[256+c];
  float4 sh = *(const float4*)&stats[384+c];
  float4 y;
  y.x = v.x*sc.x + sh.x; y.y = v.y*sc.y + sh.y;
  y.z = v.z*sc.z + sh.z; y.w = v.w*sc.w + sh.w;
  if (RELU){
    y.x=fmaxf(y.x,0.f); y.y=fmaxf(y.y,0.f); y.z=fmaxf(y.z,0.f); y.w=fmaxf(y.w,0.f);
  }
  ((float4*)Y)[i] = y;
}

__global__ __launch_bounds__(256) void k_add(const float* __restrict__ A, const float* __restrict__ B,
                                             float* __restrict__ C){
  size_t i = (size_t)blockIdx.x*256 + threadIdx.x;
  float4 a = ((const float4*)A)[i];
  float4 b = ((const float4*)B)[i];
  float4 c; c.x=a.x+b.x; c.y=a.y+b.y; c.z=a.z+b.z; c.w=a.w+b.w;
  ((float4*)C)[i] = c;
}

// ---------------- QKV -> bf16 (Q scaled), V transposed per (g,h) ----------------
__global__ __launch_bounds__(256) void k_qkvprep(const float* __restrict__ qkv,
    unsigned short* __restrict__ Qb, unsigned short* __restrict__ Kb,
    unsigned short* __restrict__ VT){
  __shared__ unsigned short Vs[128][72];
  int g = blockIdx.x, nc = blockIdx.y;
  int t = threadIdx.x;
  size_t r0 = (size_t)g*1024 + nc*64;
  const float QSC = 0.17677669529663687f * 1.4426950408889634f; // 1/sqrt(32) * log2(e)
  // Q,K halves: 64 rows x 256 cols
  #pragma unroll
  for (int i=0;i<16;i++){
    int row = i*4 + (t>>6);
    int c4 = (t&63)*4;
    float4 v = ld4(&qkv[(r0+row)*384 + c4]);
    bool isq = c4 < 128;
    float sc = isq ? QSC : 1.0f;
    ushort4 o;
    o.x = bf16rn(v.x*sc); o.y = bf16rn(v.y*sc);
    o.z = bf16rn(v.z*sc); o.w = bf16rn(v.w*sc);
    unsigned short* dst = isq ? &Qb[(r0+row)*128 + c4] : &Kb[(r0+row)*128 + (c4-128)];
    *(ushort4*)dst = o;
  }
  // V: transpose 64 n x 128 hd via LDS
  #pragma unroll
  for (int i=0;i<8;i++){
    int row = (t>>5) + i*8;
    int c4 = (t&31)*4;
    float4 v = ld4(&qkv[(r0+row)*384 + 256 + c4]);
    Vs[c4+0][row]=bf16rn(v.x); Vs[c4+1][row]=bf16rn(v.y);
    Vs[c4+2][row]=bf16rn(v.z); Vs[c4+3][row]=bf16rn(v.w);
  }
  __syncthreads();
  int hd = t & 127, half = t >> 7;
  int h = hd >> 5, d = hd & 31;
  size_t base = ((size_t)(g*4 + h)*32 + d)*1024 + nc*64 + half*32;
  #pragma unroll
  for (int j=0;j<4;j++){
    uint4 wv = *(const uint4*)&Vs[hd][half*32 + j*8];
    *(uint4*)&VT[base + j*8] = wv;
  }
}

// ---------------- MFMA flash attention ----------------
// grid (qt=16, h=4, g=32), 256 thr = 4 waves, each wave owns 16 q-rows.
// No barriers: K/Q/V fragments load straight from global bf16 (L2-resident);
// only per-wave P re-fragmentation goes through LDS.
__global__ __launch_bounds__(256) void k_flash2(const unsigned short* __restrict__ Qb,
    const unsigned short* __restrict__ Kb, const unsigned short* __restrict__ VT,
    float* __restrict__ O){
  __shared__ unsigned short Pl[4][16*72];
  int tid = threadIdx.x;
  int w = tid >> 6, l = tid & 63;
  int q = l & 15, grp = l >> 4;
  int qt = blockIdx.x, h = blockIdx.y, g = blockIdx.z;
  size_t gbase = (size_t)g*1024;
  size_t qrow0 = gbase + qt*64 + w*16;
  const unsigned short* Vp = VT + ((size_t)(g*4 + h)*32)*1024;
  bf8v qf = *(const bf8v*)&Qb[(qrow0 + q)*128 + h*32 + 8*grp];
  unsigned short* Pw = &Pl[w][0];
  float m = -1e30f, lsum = 0.f;
  f4v o0 = {0.f,0.f,0.f,0.f}, o1 = {0.f,0.f,0.f,0.f};
  for (int kt=0; kt<16; kt++){
    int k0 = kt*64;
    f4v st[4];
    #pragma unroll
    for (int t=0;t<4;t++){
      bf8v kf = *(const bf8v*)&Kb[(gbase + k0 + 16*t + q)*128 + h*32 + 8*grp];
      st[t] = __builtin_amdgcn_mfma_f32_16x16x32_bf16(kf, qf, (f4v){0.f,0.f,0.f,0.f}, 0,0,0);
    }
    // row max (qrow = l&15, replicated across the 4 lane-groups)
    float smax = st[0][0];
    #pragma unroll
    for (int t=0;t<4;t++)
      #pragma unroll
      for (int r=0;r<4;r++) smax = fmaxf(smax, st[t][r]);
    smax = fmaxf(smax, __shfl_xor(smax, 16));
    smax = fmaxf(smax, __shfl_xor(smax, 32));
    float mnew = fmaxf(m, smax);
    float alpha = exp2f(m - mnew);
    float psum = 0.f;
    #pragma unroll
    for (int t=0;t<4;t++){
      float p0 = exp2f(st[t][0]-mnew), p1 = exp2f(st[t][1]-mnew);
      float p2 = exp2f(st[t][2]-mnew), p3 = exp2f(st[t][3]-mnew);
      psum += (p0+p1)+(p2+p3);
      unsigned w0 = (unsigned)bf16rn(p0) | ((unsigned)bf16rn(p1) << 16);
      unsigned w1 = (unsigned)bf16rn(p2) | ((unsigned)bf16rn(p3) << 16);
      *(unsigned*)&Pw[q*72 + 16*t + 4*grp]     = w0;
      *(unsigned*)&Pw[q*72 + 16*t + 4*grp + 2] = w1;
    }
    psum += __shfl_xor(psum, 16);
    psum += __shfl_xor(psum, 32);
    lsum = lsum*alpha + psum;
    m = mnew;
    // rescale O accumulators (rows are 4*grp+r there)
    f4v aD;
    #pragma unroll
    for (int r=0;r<4;r++) aD[r] = __shfl(alpha, 4*grp + r);
    #pragma unroll
    for (int r=0;r<4;r++){ o0[r] *= aD[r]; o1[r] *= aD[r]; }
    // P A-frags from LDS, V B-frags from global (VT rows)
    bf8v pa0 = *(const bf8v*)&Pw[q*72 + 8*grp];
    bf8v pa1 = *(const bf8v*)&Pw[q*72 + 32 + 8*grp];
    bf8v v00 = *(const bf8v*)&Vp[(size_t)q*1024      + k0 + 8*grp];
    bf8v v01 = *(const bf8v*)&Vp[(size_t)q*1024      + k0 + 32 + 8*grp];
    bf8v v10 = *(const bf8v*)&Vp[(size_t)(16+q)*1024 + k0 + 8*grp];
    bf8v v11 = *(const bf8v*)&Vp[(size_t)(16+q)*1024 + k0 + 32 + 8*grp];
    o0 = __builtin_amdgcn_mfma_f32_16x16x32_bf16(pa0, v00, o0, 0,0,0);
    o0 = __builtin_amdgcn_mfma_f32_16x16x32_bf16(pa1, v01, o0, 0,0,0);
    o1 = __builtin_amdgcn_mfma_f32_16x16x32_bf16(pa0, v10, o1, 0,0,0);
    o1 = __builtin_amdgcn_mfma_f32_16x16x32_bf16(pa1, v11, o1, 0,0,0);
  }
  f4v lD;
  #pragma unroll
  for (int r=0;r<4;r++) lD[r] = __shfl(lsum, 4*grp + r);
  #pragma unroll
  for (int r=0;r<4;r++){
    float inv = 1.0f/lD[r];
    size_t row = qrow0 + 4*grp + r;
    O[row*HDIM + h*32 + q]      = o0[r]*inv;
    O[row*HDIM + h*32 + 16 + q] = o1[r]*inv;
  }
}

// ---------------- host ----------------
extern "C" void kernel_launch(void* const* d_in, const int* in_sizes, int n_in,
                              void* d_out, int out_size, void* d_ws, size_t ws_size,
                              hipStream_t stream){
  const float* x_in      = (const float*)d_in[0];
  const float* edge_attr = (const float*)d_in[1];
  const float* gine_w1   = (const float*)d_in[2];
  const float* gine_b1   = (const float*)d_in[3];
  const float* gine_bn_g = (const float*)d_in[4];
  const float* gine_bn_b = (const float*)d_in[5];
  const float* gine_w2   = (const float*)d_in[6];
  const float* gine_b2   = (const float*)d_in[7];
  const float* attn_wqkv = (const float*)d_in[8];
  const float* attn_bqkv = (const float*)d_in[9];
  const float* attn_wo   = (const float*)d_in[10];
  const float* attn_bo   = (const float*)d_in[11];
  const float* norm1_g   = (const float*)d_in[12];
  const float* norm1_b   = (const float*)d_in[13];
  const float* norm2_g   = (const float*)d_in[14];
  const float* norm2_b   = (const float*)d_in[15];
  const float* norm3_g   = (const float*)d_in[16];
  const float* norm3_b   = (const float*)d_in[17];
  const float* mlp_w1    = (const float*)d_in[18];
  const float* mlp_b1    = (const float*)d_in[19];
  const float* mlp_w2    = (const float*)d_in[20];
  const float* mlp_b2    = (const float*)d_in[21];
  const int* edge_index  = (const int*)d_in[22];
  const int* srcp = edge_index;
  const int* dstp = edge_index + NE;
  float* out = (float*)d_out;

  float* ws = (float*)d_ws;
  const size_t U = 4194304; // NTOT*HDIM
  float* X     = ws;
  float* AGGR  = ws + 1*U;
  float* H1    = ws + 2*U;
  float* HATTN = ws + 3*U;
  float* OBUF  = ws + 4*U;
  float* FF    = ws + 5*U;   // 2 units; also reused as bf16 QKV staging during attention
  float* QKV   = ws + 7*U;   // 3 units
  float* STATS = ws + 10*U;
  int* IW      = (int*)(STATS + 512);
  int* deg     = IW;
  int* indptr  = IW + 32768;
  int* cursor  = IW + 32768 + 32772;
  int* perm    = cursor + 32768;

  unsigned short* Qb  = (unsigned short*)(ws + 5*U);     // reuses FF space pre-FFN
  unsigned short* Kb  = Qb + (size_t)NTOT*128;
  unsigned short* VTb = Kb + (size_t)NTOT*128;

  hipMemsetAsync(deg, 0, NTOT*sizeof(int), stream);
  k_count<<<NE/256, 256, 0, stream>>>(dstp, deg);
  k_scan<<<1, 1024, 0, stream>>>(deg, indptr, cursor);
  k_fill<<<NE/256, 256, 0, stream>>>(dstp, cursor, perm);
  hipMemcpyAsync(X, x_in, (size_t)NTOT*HDIM*sizeof(float), hipMemcpyDeviceToDevice, stream);

  const int GAPPLY = (NTOT*HDIM/4)/256;
  dim3 g128(NTOT/128, 2), g256(NTOT/128, 4), g384(NTOT/128, 6);

  auto bn = [&](const float* data, const float* gg, const float* bb, float* dest, bool relu){
    hipMemsetAsync(STATS, 0, 256*sizeof(float), stream);
    k_bnstats<<<256, 128, 0, stream>>>(data, STATS);
    k_bnfinal<<<1, 128, 0, stream>>>(gg, bb, STATS);
    if (relu) k_bnapply<true ><<<GAPPLY, 256, 0, stream>>>(data, STATS, dest);
    else      k_bnapply<false><<<GAPPLY, 256, 0, stream>>>(data, STATS, dest);
  };

  for (int i=0;i<3;i++){
    const float* W1 = gine_w1 + (size_t)i*HDIM*HDIM;
    const float* B1 = gine_b1 + (size_t)i*HDIM;
    const float* W2 = gine_w2 + (size_t)i*HDIM*HDIM;
    const float* B2 = gine_b2 + (size_t)i*HDIM;
    const float* WQ = attn_wqkv + (size_t)i*3*HDIM*HDIM;
    const float* BQ = attn_bqkv + (size_t)i*3*HDIM;
    const float* WO = attn_wo + (size_t)i*HDIM*HDIM;
    const float* BO = attn_bo + (size_t)i*HDIM;
    const float* WM1 = mlp_w1 + (size_t)i*2*HDIM*HDIM;
    const float* BM1 = mlp_b1 + (size_t)i*2*HDIM;
    const float* WM2 = mlp_w2 + (size_t)i*2*HDIM*HDIM;
    const float* BM2 = mlp_b2 + (size_t)i*HDIM;

    // GINE
    k_aggr<<<NTOT, 128, 0, stream>>>(X, edge_attr, srcp, indptr, perm, AGGR);
    k_gemm<true,false,false><<<g128, 256, 0, stream>>>(X, AGGR, W1, B1, nullptr, H1, 128, 128);
    bn(H1, gine_bn_g + (size_t)i*HDIM, gine_bn_b + (size_t)i*HDIM, H1, true);
    k_gemm<false,false,true><<<g128, 256, 0, stream>>>(H1, nullptr, W2, B2, X, AGGR, 128, 128);
    bn(AGGR, norm1_g + (size_t)i*HDIM, norm1_b + (size_t)i*HDIM, H1, false); // h_local -> H1

    // attention
    k_gemm<false,false,false><<<g384, 256, 0, stream>>>(X, nullptr, WQ, BQ, nullptr, QKV, 384, 128);
    k_qkvprep<<<dim3(NGRAPH, 16), 256, 0, stream>>>(QKV, Qb, Kb, VTb);
    k_flash2<<<dim3(16, NHEAD, NGRAPH), 256, 0, stream>>>(Qb, Kb, VTb, OBUF);
    k_gemm<false,false,true><<<g128, 256, 0, stream>>>(OBUF, nullptr, WO, BO, X, AGGR, 128, 128);
    bn(AGGR, norm2_g + (size_t)i*HDIM, norm2_b + (size_t)i*HDIM, HATTN, false); // h_attn -> HATTN

    // combine + FFN
    k_add<<<GAPPLY, 256, 0, stream>>>(H1, HATTN, AGGR);
    k_gemm<false,true,false><<<g256, 256, 0, stream>>>(AGGR, nullptr, WM1, BM1, nullptr, FF, 256, 128);
    k_gemm<false,false,true><<<g128, 256, 0, stream>>>(FF, nullptr, WM2, BM2, AGGR, HATTN, 128, 256);
    float* dest = (i==2) ? out : X;
    bn(HATTN, norm3_g + (size_t)i*HDIM, norm3_b + (size_t)i*HDIM, dest, i<2);
  }
}

// Round 3
// 1261.945 us; speedup vs baseline: 1.7313x; 1.2367x over previous
//
#include <hip/hip_runtime.h>
#include <hip/hip_bf16.h>
#include <math.h>

#define NTOT 32768
#define HDIM 128
#define NE   524288
#define NGRAPH 32
#define NNODE 1024
#define NHEAD 4
#define DHEAD 32

typedef __attribute__((ext_vector_type(8))) short bf8v;
typedef __attribute__((ext_vector_type(4))) float f4v;

__device__ __forceinline__ float4 ld4(const float* p){ return *(const float4*)p; }

__device__ __forceinline__ unsigned short bf16rn(float f){
  union { float f; unsigned u; } x; x.f = f;
  unsigned r = x.u + 0x7FFF + ((x.u >> 16) & 1);
  return (unsigned short)(r >> 16);
}
__device__ __forceinline__ unsigned pk2(float a, float b){
  return (unsigned)bf16rn(a) | ((unsigned)bf16rn(b) << 16);
}

// ---------------- CSR build ----------------
__global__ void k_count(const int* __restrict__ dst, int* __restrict__ deg){
  int e = blockIdx.x*256 + threadIdx.x;
  atomicAdd(&deg[dst[e]], 1);
}

__global__ __launch_bounds__(1024) void k_scan(const int* __restrict__ deg,
                                               int* __restrict__ indptr,
                                               int* __restrict__ cursor){
  __shared__ int sm[1024];
  int t = threadIdx.x;
  int base = t*32;
  int s = 0;
  for (int j=0;j<32;j++) s += deg[base+j];
  sm[t] = s; __syncthreads();
  for (int off=1; off<1024; off<<=1){
    int v = (t>=off) ? sm[t-off] : 0;
    __syncthreads();
    sm[t] += v;
    __syncthreads();
  }
  int ex = sm[t] - s;
  for (int j=0;j<32;j++){
    int d = deg[base+j];
    indptr[base+j] = ex; cursor[base+j] = ex;
    ex += d;
  }
  if (t == 1023) indptr[NTOT] = ex;
}

__global__ void k_fill(const int* __restrict__ dst, int* __restrict__ cursor,
                       int* __restrict__ perm){
  int e = blockIdx.x*256 + threadIdx.x;
  int pos = atomicAdd(&cursor[dst[e]], 1);
  perm[pos] = e;
}

// aggr[n][:] = sum over incoming edges of relu(x[src] + ea[e]); 32 lanes/node, float4
__global__ __launch_bounds__(256) void k_aggr(const float* __restrict__ x,
                       const float* __restrict__ ea,
                       const int* __restrict__ src, const int* __restrict__ indptr,
                       const int* __restrict__ perm, float* __restrict__ aggr){
  int tid = threadIdx.x;
  int n = blockIdx.x*8 + (tid>>5);
  int c4 = (tid&31)*4;
  int p0 = indptr[n], p1 = indptr[n+1];
  float4 acc = make_float4(0.f,0.f,0.f,0.f);
  for (int p=p0;p<p1;p++){
    int e = perm[p];
    int s = src[e];
    float4 xv = ld4(&x[(size_t)s*HDIM + c4]);
    float4 ev = ld4(&ea[(size_t)e*HDIM + c4]);
    acc.x += fmaxf(xv.x+ev.x, 0.f);
    acc.y += fmaxf(xv.y+ev.y, 0.f);
    acc.z += fmaxf(xv.z+ev.z, 0.f);
    acc.w += fmaxf(xv.w+ev.w, 0.f);
  }
  *(float4*)&aggr[(size_t)n*HDIM + c4] = acc;
}

// ---------------- MFMA bf16 GEMM ----------------
// C[M,N] = act( stage(A (+A2) | bn-transform) @ W^T + bias (+Ep) )
// BM=BN=128, BK=32, 256 thr = 4 waves, each wave 64x64 via 4x4 16x16x32 frags.
template<bool ADDA, bool BNA, bool RELU, bool EP>
__global__ __launch_bounds__(256) void k_gemm16(const float* __restrict__ A,
    const float* __restrict__ A2, const float* __restrict__ bnst,
    const float* __restrict__ W, const float* __restrict__ bias,
    const float* __restrict__ Ep, float* __restrict__ C, int N, int K){
  __shared__ uint4 Asm[128*4];
  __shared__ uint4 Wsm[128*4];
  int tid = threadIdx.x;
  int w = tid>>6, l = tid&63;
  int q = l&15, g = l>>4;
  int m0 = blockIdx.x*128, n0 = blockIdx.y*128;
  int wr = (w>>1)*64, wc = (w&1)*64;
  f4v acc[4][4];
  #pragma unroll
  for (int i=0;i<4;i++)
    #pragma unroll
    for (int j=0;j<4;j++) acc[i][j] = (f4v){0.f,0.f,0.f,0.f};
  int srow = tid & 127;
  int sgh  = tid >> 7;          // 0/1 -> k chunks {0,1} or {2,3}
  int sswz = (srow>>1)&3;

  for (int kc=0; kc<K; kc+=32){
    const float* pa = &A[(size_t)(m0+srow)*K + kc + sgh*16];
    float4 v0=ld4(pa), v1=ld4(pa+4), v2=ld4(pa+8), v3=ld4(pa+12);
    if (ADDA){
      const float* pb = &A2[(size_t)(m0+srow)*K + kc + sgh*16];
      float4 u0=ld4(pb), u1=ld4(pb+4), u2=ld4(pb+8), u3=ld4(pb+12);
      v0.x+=u0.x; v0.y+=u0.y; v0.z+=u0.z; v0.w+=u0.w;
      v1.x+=u1.x; v1.y+=u1.y; v1.z+=u1.z; v1.w+=u1.w;
      v2.x+=u2.x; v2.y+=u2.y; v2.z+=u2.z; v2.w+=u2.w;
      v3.x+=u3.x; v3.y+=u3.y; v3.z+=u3.z; v3.w+=u3.w;
    }
    if (BNA){
      int kb = kc + sgh*16;
      float4 s0=ld4(&bnst[256+kb]),  s1=ld4(&bnst[256+kb+4]);
      float4 s2=ld4(&bnst[256+kb+8]),s3=ld4(&bnst[256+kb+12]);
      float4 h0=ld4(&bnst[384+kb]),  h1=ld4(&bnst[384+kb+4]);
      float4 h2=ld4(&bnst[384+kb+8]),h3=ld4(&bnst[384+kb+12]);
      v0.x=fmaxf(v0.x*s0.x+h0.x,0.f); v0.y=fmaxf(v0.y*s0.y+h0.y,0.f);
      v0.z=fmaxf(v0.z*s0.z+h0.z,0.f); v0.w=fmaxf(v0.w*s0.w+h0.w,0.f);
      v1.x=fmaxf(v1.x*s1.x+h1.x,0.f); v1.y=fmaxf(v1.y*s1.y+h1.y,0.f);
      v1.z=fmaxf(v1.z*s1.z+h1.z,0.f); v1.w=fmaxf(v1.w*s1.w+h1.w,0.f);
      v2.x=fmaxf(v2.x*s2.x+h2.x,0.f); v2.y=fmaxf(v2.y*s2.y+h2.y,0.f);
      v2.z=fmaxf(v2.z*s2.z+h2.z,0.f); v2.w=fmaxf(v2.w*s2.w+h2.w,0.f);
      v3.x=fmaxf(v3.x*s3.x+h3.x,0.f); v3.y=fmaxf(v3.y*s3.y+h3.y,0.f);
      v3.z=fmaxf(v3.z*s3.z+h3.z,0.f); v3.w=fmaxf(v3.w*s3.w+h3.w,0.f);
    }
    uint4 ca, cb;
    ca.x=pk2(v0.x,v0.y); ca.y=pk2(v0.z,v0.w); ca.z=pk2(v1.x,v1.y); ca.w=pk2(v1.z,v1.w);
    cb.x=pk2(v2.x,v2.y); cb.y=pk2(v2.z,v2.w); cb.z=pk2(v3.x,v3.y); cb.w=pk2(v3.z,v3.w);
    const float* pw = &W[(size_t)(n0+srow)*K + kc + sgh*16];
    float4 w0=ld4(pw), w1=ld4(pw+4), w2=ld4(pw+8), w3=ld4(pw+12);
    uint4 da, db;
    da.x=pk2(w0.x,w0.y); da.y=pk2(w0.z,w0.w); da.z=pk2(w1.x,w1.y); da.w=pk2(w1.z,w1.w);
    db.x=pk2(w2.x,w2.y); db.y=pk2(w2.z,w2.w); db.z=pk2(w3.x,w3.y); db.w=pk2(w3.z,w3.w);
    __syncthreads();
    Asm[srow*4 + ((2*sgh  )^sswz)] = ca;
    Asm[srow*4 + ((2*sgh+1)^sswz)] = cb;
    Wsm[srow*4 + ((2*sgh  )^sswz)] = da;
    Wsm[srow*4 + ((2*sgh+1)^sswz)] = db;
    __syncthreads();
    bf8v af[4], bf[4];
    #pragma unroll
    for (int mt=0;mt<4;mt++){
      int R = wr + 16*mt + q;
      af[mt] = *(const bf8v*)&Asm[R*4 + (g ^ ((R>>1)&3))];
    }
    #pragma unroll
    for (int nt=0;nt<4;nt++){
      int R = wc + 16*nt + q;
      bf[nt] = *(const bf8v*)&Wsm[R*4 + (g ^ ((R>>1)&3))];
    }
    #pragma unroll
    for (int mt=0;mt<4;mt++)
      #pragma unroll
      for (int nt=0;nt<4;nt++)
        acc[mt][nt] = __builtin_amdgcn_mfma_f32_16x16x32_bf16(af[mt], bf[nt], acc[mt][nt], 0,0,0);
  }
  float bbv[4];
  #pragma unroll
  for (int nt=0;nt<4;nt++) bbv[nt] = bias[n0 + wc + 16*nt + q];
  #pragma unroll
  for (int mt=0;mt<4;mt++){
    int row0 = m0 + wr + 16*mt + 4*g;
    #pragma unroll
    for (int nt=0;nt<4;nt++){
      int col = n0 + wc + 16*nt + q;
      #pragma unroll
      for (int r=0;r<4;r++){
        size_t off = (size_t)(row0+r)*N + col;
        float v = acc[mt][nt][r] + bbv[nt];
        if (EP) v += Ep[off];
        if (RELU) v = fmaxf(v, 0.f);
        C[off] = v;
      }
    }
  }
}

// ---------------- BatchNorm (slot: [sum,sq,sc,sh] x 128) ----------------
__global__ __launch_bounds__(128) void k_bnstats(const float* __restrict__ X, float* __restrict__ slot){
  int f = threadIdx.x;
  size_t r0 = (size_t)blockIdx.x*128;
  float s=0.f, q=0.f;
  for (int r=0;r<128;r++){
    float v = X[(r0+r)*HDIM + f];
    s += v; q += v*v;
  }
  atomicAdd(&slot[f], s);
  atomicAdd(&slot[128+f], q);
}

__global__ __launch_bounds__(128) void k_bnfinal(const float* __restrict__ g, const float* __restrict__ b,
                                                 float* __restrict__ slot){
  int f = threadIdx.x;
  const float invn = 1.0f/32768.0f;
  float mean = slot[f]*invn;
  float var  = slot[128+f]*invn - mean*mean;
  float sc = g[f] * rsqrtf(var + 1e-5f);
  slot[256+f] = sc;
  slot[384+f] = b[f] - mean*sc;
}

template<bool RELU>
__global__ __launch_bounds__(256) void k_bnapply(const float* __restrict__ X,
                                                 const float* __restrict__ slot,
                                                 float* __restrict__ Y){
  size_t i = (size_t)blockIdx.x*256 + threadIdx.x;
  int c = (int)(i & 31) * 4;
  float4 v = ((const float4*)X)[i];
  float4 sc = *(const float4*)&slot[256+c];
  float4 sh = *(const float4*)&slot[384+c];
  float4 y;
  y.x = v.x*sc.x + sh.x; y.y = v.y*sc.y + sh.y;
  y.z = v.z*sc.z + sh.z; y.w = v.w*sc.w + sh.w;
  if (RELU){
    y.x=fmaxf(y.x,0.f); y.y=fmaxf(y.y,0.f); y.z=fmaxf(y.z,0.f); y.w=fmaxf(y.w,0.f);
  }
  ((float4*)Y)[i] = y;
}

// out = bn(A,slot1) + bn(B,slot2)
__global__ __launch_bounds__(256) void k_add2bn(const float* __restrict__ A, const float* __restrict__ s1,
                                                const float* __restrict__ B, const float* __restrict__ s2,
                                                float* __restrict__ C){
  size_t i = (size_t)blockIdx.x*256 + threadIdx.x;
  int c = (int)(i & 31) * 4;
  float4 a = ((const float4*)A)[i];
  float4 b = ((const float4*)B)[i];
  float4 c1 = *(const float4*)&s1[256+c], d1 = *(const float4*)&s1[384+c];
  float4 c2 = *(const float4*)&s2[256+c], d2 = *(const float4*)&s2[384+c];
  float4 y;
  y.x = a.x*c1.x+d1.x + b.x*c2.x+d2.x;
  y.y = a.y*c1.y+d1.y + b.y*c2.y+d2.y;
  y.z = a.z*c1.z+d1.z + b.z*c2.z+d2.z;
  y.w = a.w*c1.w+d1.w + b.w*c2.w+d2.w;
  ((float4*)C)[i] = y;
}

// ---------------- QKV -> bf16 (Q scaled), V transposed per (g,h) ----------------
__global__ __launch_bounds__(256) void k_qkvprep(const float* __restrict__ qkv,
    unsigned short* __restrict__ Qb, unsigned short* __restrict__ Kb,
    unsigned short* __restrict__ VT){
  __shared__ unsigned short Vs[128][72];
  int g = blockIdx.x, nc = blockIdx.y;
  int t = threadIdx.x;
  size_t r0 = (size_t)g*1024 + nc*64;
  const float QSC = 0.17677669529663687f * 1.4426950408889634f; // 1/sqrt(32) * log2(e)
  #pragma unroll
  for (int i=0;i<16;i++){
    int row = i*4 + (t>>6);
    int c4 = (t&63)*4;
    float4 v = ld4(&qkv[(r0+row)*384 + c4]);
    bool isq = c4 < 128;
    float sc = isq ? QSC : 1.0f;
    ushort4 o;
    o.x = bf16rn(v.x*sc); o.y = bf16rn(v.y*sc);
    o.z = bf16rn(v.z*sc); o.w = bf16rn(v.w*sc);
    unsigned short* dst = isq ? &Qb[(r0+row)*128 + c4] : &Kb[(r0+row)*128 + (c4-128)];
    *(ushort4*)dst = o;
  }
  #pragma unroll
  for (int i=0;i<8;i++){
    int row = (t>>5) + i*8;
    int c4 = (t&31)*4;
    float4 v = ld4(&qkv[(r0+row)*384 + 256 + c4]);
    Vs[c4+0][row]=bf16rn(v.x); Vs[c4+1][row]=bf16rn(v.y);
    Vs[c4+2][row]=bf16rn(v.z); Vs[c4+3][row]=bf16rn(v.w);
  }
  __syncthreads();
  int hd = t & 127, half = t >> 7;
  size_t base = ((size_t)(g*4 + (hd>>5))*32 + (hd&31))*1024 + nc*64 + half*32;
  #pragma unroll
  for (int j=0;j<4;j++){
    uint4 wv = *(const uint4*)&Vs[hd][half*32 + j*8];
    *(uint4*)&VT[base + j*8] = wv;
  }
}

// ---------------- MFMA flash attention ----------------
__global__ __launch_bounds__(256) void k_flash2(const unsigned short* __restrict__ Qb,
    const unsigned short* __restrict__ Kb, const unsigned short* __restrict__ VT,
    float* __restrict__ O){
  __shared__ unsigned short Pl[4][16*72];
  int tid = threadIdx.x;
  int w = tid >> 6, l = tid & 63;
  int q = l & 15, grp = l >> 4;
  int qt = blockIdx.x, h = blockIdx.y, g = blockIdx.z;
  size_t gbase = (size_t)g*1024;
  size_t qrow0 = gbase + qt*64 + w*16;
  const unsigned short* Vp = VT + ((size_t)(g*4 + h)*32)*1024;
  bf8v qf = *(const bf8v*)&Qb[(qrow0 + q)*128 + h*32 + 8*grp];
  unsigned short* Pw = &Pl[w][0];
  float m = -1e30f, lsum = 0.f;
  f4v o0 = {0.f,0.f,0.f,0.f}, o1 = {0.f,0.f,0.f,0.f};
  for (int kt=0; kt<16; kt++){
    int k0 = kt*64;
    f4v st[4];
    #pragma unroll
    for (int t=0;t<4;t++){
      bf8v kf = *(const bf8v*)&Kb[(gbase + k0 + 16*t + q)*128 + h*32 + 8*grp];
      st[t] = __builtin_amdgcn_mfma_f32_16x16x32_bf16(kf, qf, (f4v){0.f,0.f,0.f,0.f}, 0,0,0);
    }
    float smax = st[0][0];
    #pragma unroll
    for (int t=0;t<4;t++)
      #pragma unroll
      for (int r=0;r<4;r++) smax = fmaxf(smax, st[t][r]);
    smax = fmaxf(smax, __shfl_xor(smax, 16));
    smax = fmaxf(smax, __shfl_xor(smax, 32));
    float mnew = fmaxf(m, smax);
    float alpha = exp2f(m - mnew);
    float psum = 0.f;
    #pragma unroll
    for (int t=0;t<4;t++){
      float p0 = exp2f(st[t][0]-mnew), p1 = exp2f(st[t][1]-mnew);
      float p2 = exp2f(st[t][2]-mnew), p3 = exp2f(st[t][3]-mnew);
      psum += (p0+p1)+(p2+p3);
      unsigned w0 = (unsigned)bf16rn(p0) | ((unsigned)bf16rn(p1) << 16);
      unsigned w1 = (unsigned)bf16rn(p2) | ((unsigned)bf16rn(p3) << 16);
      *(unsigned*)&Pw[q*72 + 16*t + 4*grp]     = w0;
      *(unsigned*)&Pw[q*72 + 16*t + 4*grp + 2] = w1;
    }
    psum += __shfl_xor(psum, 16);
    psum += __shfl_xor(psum, 32);
    lsum = lsum*alpha + psum;
    m = mnew;
    f4v aD;
    #pragma unroll
    for (int r=0;r<4;r++) aD[r] = __shfl(alpha, 4*grp + r);
    #pragma unroll
    for (int r=0;r<4;r++){ o0[r] *= aD[r]; o1[r] *= aD[r]; }
    bf8v pa0 = *(const bf8v*)&Pw[q*72 + 8*grp];
    bf8v pa1 = *(const bf8v*)&Pw[q*72 + 32 + 8*grp];
    bf8v v00 = *(const bf8v*)&Vp[(size_t)q*1024      + k0 + 8*grp];
    bf8v v01 = *(const bf8v*)&Vp[(size_t)q*1024      + k0 + 32 + 8*grp];
    bf8v v10 = *(const bf8v*)&Vp[(size_t)(16+q)*1024 + k0 + 8*grp];
    bf8v v11 = *(const bf8v*)&Vp[(size_t)(16+q)*1024 + k0 + 32 + 8*grp];
    o0 = __builtin_amdgcn_mfma_f32_16x16x32_bf16(pa0, v00, o0, 0,0,0);
    o0 = __builtin_amdgcn_mfma_f32_16x16x32_bf16(pa1, v01, o0, 0,0,0);
    o1 = __builtin_amdgcn_mfma_f32_16x16x32_bf16(pa0, v10, o1, 0,0,0);
    o1 = __builtin_amdgcn_mfma_f32_16x16x32_bf16(pa1, v11, o1, 0,0,0);
  }
  f4v lD;
  #pragma unroll
  for (int r=0;r<4;r++) lD[r] = __shfl(lsum, 4*grp + r);
  #pragma unroll
  for (int r=0;r<4;r++){
    float inv = 1.0f/lD[r];
    size_t row = qrow0 + 4*grp + r;
    O[row*HDIM + h*32 + q]      = o0[r]*inv;
    O[row*HDIM + h*32 + 16 + q] = o1[r]*inv;
  }
}

// ---------------- host ----------------
extern "C" void kernel_launch(void* const* d_in, const int* in_sizes, int n_in,
                              void* d_out, int out_size, void* d_ws, size_t ws_size,
                              hipStream_t stream){
  const float* x_in      = (const float*)d_in[0];
  const float* edge_attr = (const float*)d_in[1];
  const float* gine_w1   = (const float*)d_in[2];
  const float* gine_b1   = (const float*)d_in[3];
  const float* gine_bn_g = (const float*)d_in[4];
  const float* gine_bn_b = (const float*)d_in[5];
  const float* gine_w2   = (const float*)d_in[6];
  const float* gine_b2   = (const float*)d_in[7];
  const float* attn_wqkv = (const float*)d_in[8];
  const float* attn_bqkv = (const float*)d_in[9];
  const float* attn_wo   = (const float*)d_in[10];
  const float* attn_bo   = (const float*)d_in[11];
  const float* norm1_g   = (const float*)d_in[12];
  const float* norm1_b   = (const float*)d_in[13];
  const float* norm2_g   = (const float*)d_in[14];
  const float* norm2_b   = (const float*)d_in[15];
  const float* norm3_g   = (const float*)d_in[16];
  const float* norm3_b   = (const float*)d_in[17];
  const float* mlp_w1    = (const float*)d_in[18];
  const float* mlp_b1    = (const float*)d_in[19];
  const float* mlp_w2    = (const float*)d_in[20];
  const float* mlp_b2    = (const float*)d_in[21];
  const int* edge_index  = (const int*)d_in[22];
  const int* srcp = edge_index;
  const int* dstp = edge_index + NE;
  float* out = (float*)d_out;

  float* ws = (float*)d_ws;
  const size_t U = 4194304; // NTOT*HDIM floats
  float* X     = ws;
  float* AGGR  = ws + 1*U;
  float* H1    = ws + 2*U;   // also flash O buffer
  float* H2    = ws + 3*U;   // attn pre-norm, then mlp2 out
  float* OUT   = ws + 4*U;   // combined h_local+h_attn
  float* FF    = ws + 5*U;   // 2 units
  float* QKV   = ws + 7*U;   // 3 units
  unsigned short* Qb  = (unsigned short*)(ws + 10*U);
  unsigned short* Kb  = Qb + (size_t)NTOT*128;
  unsigned short* VTb = Kb + (size_t)NTOT*128;
  float* STATS = ws + 12*U;  // 12 slots x 512 floats
  int* IW      = (int*)(STATS + 12*512);
  int* deg     = IW;
  int* indptr  = IW + 32768;
  int* cursor  = IW + 32768 + 32772;
  int* perm    = cursor + 32768;

  hipMemsetAsync(STATS, 0, 12*512*sizeof(float), stream);
  hipMemsetAsync(deg, 0, NTOT*sizeof(int), stream);
  k_count<<<NE/256, 256, 0, stream>>>(dstp, deg);
  k_scan<<<1, 1024, 0, stream>>>(deg, indptr, cursor);
  k_fill<<<NE/256, 256, 0, stream>>>(dstp, cursor, perm);
  hipMemcpyAsync(X, x_in, (size_t)NTOT*HDIM*sizeof(float), hipMemcpyDeviceToDevice, stream);

  const int GAPPLY = (NTOT*HDIM/4)/256;
  dim3 gemmg1(NTOT/128, 1), gemmg2(NTOT/128, 2), gemmg3(NTOT/128, 3);

  for (int i=0;i<3;i++){
    const float* W1 = gine_w1 + (size_t)i*HDIM*HDIM;
    const float* B1 = gine_b1 + (size_t)i*HDIM;
    const float* W2 = gine_w2 + (size_t)i*HDIM*HDIM;
    const float* B2 = gine_b2 + (size_t)i*HDIM;
    const float* WQ = attn_wqkv + (size_t)i*3*HDIM*HDIM;
    const float* BQ = attn_bqkv + (size_t)i*3*HDIM;
    const float* WO = attn_wo + (size_t)i*HDIM*HDIM;
    const float* BO = attn_bo + (size_t)i*HDIM;
    const float* WM1 = mlp_w1 + (size_t)i*2*HDIM*HDIM;
    const float* BM1 = mlp_b1 + (size_t)i*2*HDIM;
    const float* WM2 = mlp_w2 + (size_t)i*2*HDIM*HDIM;
    const float* BM2 = mlp_b2 + (size_t)i*HDIM;
    float* S0 = STATS + (size_t)(i*4+0)*512;
    float* S1 = STATS + (size_t)(i*4+1)*512;
    float* S2 = STATS + (size_t)(i*4+2)*512;
    float* S3 = STATS + (size_t)(i*4+3)*512;

    // ---- GINE
    k_aggr<<<NTOT/8, 256, 0, stream>>>(X, edge_attr, srcp, indptr, perm, AGGR);
    k_gemm16<true,false,false,false><<<gemmg1, 256, 0, stream>>>(X, AGGR, nullptr, W1, B1, nullptr, H1, 128, 128);
    k_bnstats<<<256, 128, 0, stream>>>(H1, S0);
    k_bnfinal<<<1, 128, 0, stream>>>(gine_bn_g + (size_t)i*HDIM, gine_bn_b + (size_t)i*HDIM, S0);
    k_gemm16<false,true,false,true><<<gemmg1, 256, 0, stream>>>(H1, nullptr, S0, W2, B2, X, AGGR, 128, 128);
    k_bnstats<<<256, 128, 0, stream>>>(AGGR, S1);
    k_bnfinal<<<1, 128, 0, stream>>>(norm1_g + (size_t)i*HDIM, norm1_b + (size_t)i*HDIM, S1);

    // ---- attention
    k_gemm16<false,false,false,false><<<gemmg3, 256, 0, stream>>>(X, nullptr, nullptr, WQ, BQ, nullptr, QKV, 384, 128);
    k_qkvprep<<<dim3(NGRAPH, 16), 256, 0, stream>>>(QKV, Qb, Kb, VTb);
    k_flash2<<<dim3(16, NHEAD, NGRAPH), 256, 0, stream>>>(Qb, Kb, VTb, H1);
    k_gemm16<false,false,false,true><<<gemmg1, 256, 0, stream>>>(H1, nullptr, nullptr, WO, BO, X, H2, 128, 128);
    k_bnstats<<<256, 128, 0, stream>>>(H2, S2);
    k_bnfinal<<<1, 128, 0, stream>>>(norm2_g + (size_t)i*HDIM, norm2_b + (size_t)i*HDIM, S2);

    // ---- combine + FFN
    k_add2bn<<<GAPPLY, 256, 0, stream>>>(AGGR, S1, H2, S2, OUT);
    k_gemm16<false,false,true,false><<<gemmg2, 256, 0, stream>>>(OUT, nullptr, nullptr, WM1, BM1, nullptr, FF, 256, 128);
    k_gemm16<false,false,false,true><<<gemmg1, 256, 0, stream>>>(FF, nullptr, nullptr, WM2, BM2, OUT, H2, 128, 256);
    k_bnstats<<<256, 128, 0, stream>>>(H2, S3);
    k_bnfinal<<<1, 128, 0, stream>>>(norm3_g + (size_t)i*HDIM, norm3_b + (size_t)i*HDIM, S3);
    float* dest = (i==2) ? out : X;
    if (i<2) k_bnapply<true ><<<GAPPLY, 256, 0, stream>>>(H2, S3, dest);
    else     k_bnapply<false><<<GAPPLY, 256, 0, stream>>>(H2, S3, dest);
  }
}

// Round 4
// 1161.591 us; speedup vs baseline: 1.8809x; 1.0864x over previous
//
#include <hip/hip_runtime.h>
#include <hip/hip_bf16.h>
#include <math.h>

#define NTOT 32768
#define HDIM 128
#define NE   524288
#define NGRAPH 32
#define NNODE 1024
#define NHEAD 4
#define DHEAD 32

typedef __attribute__((ext_vector_type(8))) short bf8v;
typedef __attribute__((ext_vector_type(4))) float f4v;

__device__ __forceinline__ float4 ld4(const float* p){ return *(const float4*)p; }

__device__ __forceinline__ unsigned short bf16rn(float f){
  union { float f; unsigned u; } x; x.f = f;
  unsigned r = x.u + 0x7FFF + ((x.u >> 16) & 1);
  return (unsigned short)(r >> 16);
}
// hardware packed cvt: D[15:0]=bf16(a), D[31:16]=bf16(b)
__device__ __forceinline__ unsigned pk2(float a, float b){
  unsigned r;
  asm("v_cvt_pk_bf16_f32 %0, %1, %2" : "=v"(r) : "v"(a), "v"(b));
  return r;
}
__device__ __forceinline__ float bf2f(unsigned short u){
  union { unsigned u; float f; } x; x.u = ((unsigned)u) << 16;
  return x.f;
}

// ---------------- CSR build ----------------
__global__ void k_count(const int* __restrict__ dst, int* __restrict__ deg){
  int e = blockIdx.x*256 + threadIdx.x;
  atomicAdd(&deg[dst[e]], 1);
}

__global__ __launch_bounds__(1024) void k_scan(const int* __restrict__ deg,
                                               int* __restrict__ indptr,
                                               int* __restrict__ cursor){
  __shared__ int sm[1024];
  int t = threadIdx.x;
  int base = t*32;
  int s = 0;
  for (int j=0;j<32;j++) s += deg[base+j];
  sm[t] = s; __syncthreads();
  for (int off=1; off<1024; off<<=1){
    int v = (t>=off) ? sm[t-off] : 0;
    __syncthreads();
    sm[t] += v;
    __syncthreads();
  }
  int ex = sm[t] - s;
  for (int j=0;j<32;j++){
    int d = deg[base+j];
    indptr[base+j] = ex; cursor[base+j] = ex;
    ex += d;
  }
  if (t == 1023) indptr[NTOT] = ex;
}

__global__ void k_fill(const int* __restrict__ dst, int* __restrict__ cursor,
                       int* __restrict__ perm){
  int e = blockIdx.x*256 + threadIdx.x;
  int pos = atomicAdd(&cursor[dst[e]], 1);
  perm[pos] = e;
}

// one-time: permute edge_attr into CSR order as bf16; permute src too
__global__ __launch_bounds__(256) void k_eaprep(const float* __restrict__ ea,
    const int* __restrict__ src, const int* __restrict__ perm,
    unsigned short* __restrict__ EAb, int* __restrict__ SRCp){
  int tid = threadIdx.x;
  int p = blockIdx.x*8 + (tid>>5);
  int c4 = (tid&31)*4;
  int e = perm[p];
  float4 v = ld4(&ea[(size_t)e*HDIM + c4]);
  uint2 o; o.x = pk2(v.x, v.y); o.y = pk2(v.z, v.w);
  *(uint2*)&EAb[(size_t)p*HDIM + c4] = o;
  if ((tid&31) == 0) SRCp[p] = src[e];
}

// aggr[n][:] = sum over CSR-ordered edges of relu(x[src] + ea); sequential bf16 ea
__global__ __launch_bounds__(256) void k_aggr(const float* __restrict__ x,
                       const unsigned short* __restrict__ EAb,
                       const int* __restrict__ SRCp, const int* __restrict__ indptr,
                       float* __restrict__ aggr){
  int tid = threadIdx.x;
  int n = blockIdx.x*8 + (tid>>5);
  int c4 = (tid&31)*4;
  int p0 = indptr[n], p1 = indptr[n+1];
  float4 acc = make_float4(0.f,0.f,0.f,0.f);
  for (int p=p0;p<p1;p++){
    int s = SRCp[p];
    uint2 ev = *(const uint2*)&EAb[(size_t)p*HDIM + c4];
    float4 xv = ld4(&x[(size_t)s*HDIM + c4]);
    acc.x += fmaxf(xv.x + bf2f((unsigned short)(ev.x & 0xffff)), 0.f);
    acc.y += fmaxf(xv.y + bf2f((unsigned short)(ev.x >> 16)), 0.f);
    acc.z += fmaxf(xv.z + bf2f((unsigned short)(ev.y & 0xffff)), 0.f);
    acc.w += fmaxf(xv.w + bf2f((unsigned short)(ev.y >> 16)), 0.f);
  }
  *(float4*)&aggr[(size_t)n*HDIM + c4] = acc;
}

// ---------------- MFMA bf16 GEMM ----------------
// C[M,N] = act( stage(A (+A2) | bn) @ W^T + bias (+Ep) ); optional fused col stats
template<bool ADDA, bool BNA, bool RELU, bool EP, bool STATS>
__global__ __launch_bounds__(256) void k_gemm16(const float* __restrict__ A,
    const float* __restrict__ A2, const float* __restrict__ bnst,
    const float* __restrict__ W, const float* __restrict__ bias,
    const float* __restrict__ Ep, float* __restrict__ C, float* __restrict__ slot,
    int N, int K){
  __shared__ uint4 Asm[128*4];
  __shared__ uint4 Wsm[128*4];
  __shared__ float sred[256];
  int tid = threadIdx.x;
  int w = tid>>6, l = tid&63;
  int q = l&15, g = l>>4;
  int m0 = blockIdx.x*128, n0 = blockIdx.y*128;
  int wr = (w>>1)*64, wc = (w&1)*64;
  f4v acc[4][4];
  #pragma unroll
  for (int i=0;i<4;i++)
    #pragma unroll
    for (int j=0;j<4;j++) acc[i][j] = (f4v){0.f,0.f,0.f,0.f};
  int srow = tid & 127;
  int sgh  = tid >> 7;
  int sswz = (srow>>1)&3;

  for (int kc=0; kc<K; kc+=32){
    const float* pa = &A[(size_t)(m0+srow)*K + kc + sgh*16];
    float4 v0=ld4(pa), v1=ld4(pa+4), v2=ld4(pa+8), v3=ld4(pa+12);
    if (ADDA){
      const float* pb = &A2[(size_t)(m0+srow)*K + kc + sgh*16];
      float4 u0=ld4(pb), u1=ld4(pb+4), u2=ld4(pb+8), u3=ld4(pb+12);
      v0.x+=u0.x; v0.y+=u0.y; v0.z+=u0.z; v0.w+=u0.w;
      v1.x+=u1.x; v1.y+=u1.y; v1.z+=u1.z; v1.w+=u1.w;
      v2.x+=u2.x; v2.y+=u2.y; v2.z+=u2.z; v2.w+=u2.w;
      v3.x+=u3.x; v3.y+=u3.y; v3.z+=u3.z; v3.w+=u3.w;
    }
    if (BNA){
      int kb = kc + sgh*16;
      float4 s0=ld4(&bnst[256+kb]),  s1=ld4(&bnst[256+kb+4]);
      float4 s2=ld4(&bnst[256+kb+8]),s3=ld4(&bnst[256+kb+12]);
      float4 h0=ld4(&bnst[384+kb]),  h1=ld4(&bnst[384+kb+4]);
      float4 h2=ld4(&bnst[384+kb+8]),h3=ld4(&bnst[384+kb+12]);
      v0.x=fmaxf(v0.x*s0.x+h0.x,0.f); v0.y=fmaxf(v0.y*s0.y+h0.y,0.f);
      v0.z=fmaxf(v0.z*s0.z+h0.z,0.f); v0.w=fmaxf(v0.w*s0.w+h0.w,0.f);
      v1.x=fmaxf(v1.x*s1.x+h1.x,0.f); v1.y=fmaxf(v1.y*s1.y+h1.y,0.f);
      v1.z=fmaxf(v1.z*s1.z+h1.z,0.f); v1.w=fmaxf(v1.w*s1.w+h1.w,0.f);
      v2.x=fmaxf(v2.x*s2.x+h2.x,0.f); v2.y=fmaxf(v2.y*s2.y+h2.y,0.f);
      v2.z=fmaxf(v2.z*s2.z+h2.z,0.f); v2.w=fmaxf(v2.w*s2.w+h2.w,0.f);
      v3.x=fmaxf(v3.x*s3.x+h3.x,0.f); v3.y=fmaxf(v3.y*s3.y+h3.y,0.f);
      v3.z=fmaxf(v3.z*s3.z+h3.z,0.f); v3.w=fmaxf(v3.w*s3.w+h3.w,0.f);
    }
    uint4 ca, cb;
    ca.x=pk2(v0.x,v0.y); ca.y=pk2(v0.z,v0.w); ca.z=pk2(v1.x,v1.y); ca.w=pk2(v1.z,v1.w);
    cb.x=pk2(v2.x,v2.y); cb.y=pk2(v2.z,v2.w); cb.z=pk2(v3.x,v3.y); cb.w=pk2(v3.z,v3.w);
    const float* pw = &W[(size_t)(n0+srow)*K + kc + sgh*16];
    float4 w0=ld4(pw), w1=ld4(pw+4), w2=ld4(pw+8), w3=ld4(pw+12);
    uint4 da, db;
    da.x=pk2(w0.x,w0.y); da.y=pk2(w0.z,w0.w); da.z=pk2(w1.x,w1.y); da.w=pk2(w1.z,w1.w);
    db.x=pk2(w2.x,w2.y); db.y=pk2(w2.z,w2.w); db.z=pk2(w3.x,w3.y); db.w=pk2(w3.z,w3.w);
    __syncthreads();
    Asm[srow*4 + ((2*sgh  )^sswz)] = ca;
    Asm[srow*4 + ((2*sgh+1)^sswz)] = cb;
    Wsm[srow*4 + ((2*sgh  )^sswz)] = da;
    Wsm[srow*4 + ((2*sgh+1)^sswz)] = db;
    __syncthreads();
    bf8v af[4], bfv[4];
    #pragma unroll
    for (int mt=0;mt<4;mt++){
      int R = wr + 16*mt + q;
      af[mt] = *(const bf8v*)&Asm[R*4 + (g ^ ((R>>1)&3))];
    }
    #pragma unroll
    for (int nt=0;nt<4;nt++){
      int R = wc + 16*nt + q;
      bfv[nt] = *(const bf8v*)&Wsm[R*4 + (g ^ ((R>>1)&3))];
    }
    #pragma unroll
    for (int mt=0;mt<4;mt++)
      #pragma unroll
      for (int nt=0;nt<4;nt++)
        acc[mt][nt] = __builtin_amdgcn_mfma_f32_16x16x32_bf16(af[mt], bfv[nt], acc[mt][nt], 0,0,0);
  }
  float bbv[4];
  #pragma unroll
  for (int nt=0;nt<4;nt++) bbv[nt] = bias[n0 + wc + 16*nt + q];
  float csum[4] = {0.f,0.f,0.f,0.f}, csq[4] = {0.f,0.f,0.f,0.f};
  #pragma unroll
  for (int mt=0;mt<4;mt++){
    int row0 = m0 + wr + 16*mt + 4*g;
    #pragma unroll
    for (int nt=0;nt<4;nt++){
      int col = n0 + wc + 16*nt + q;
      #pragma unroll
      for (int r=0;r<4;r++){
        size_t off = (size_t)(row0+r)*N + col;
        float v = acc[mt][nt][r] + bbv[nt];
        if (EP) v += Ep[off];
        if (RELU) v = fmaxf(v, 0.f);
        C[off] = v;
        if (STATS){ csum[nt] += v; csq[nt] += v*v; }
      }
    }
  }
  if (STATS){
    if (tid < 128){ sred[tid] = 0.f; sred[128+tid] = 0.f; }
    __syncthreads();
    #pragma unroll
    for (int nt=0;nt<4;nt++){
      int col = wc + 16*nt + q;
      atomicAdd(&sred[col], csum[nt]);
      atomicAdd(&sred[128+col], csq[nt]);
    }
    __syncthreads();
    if (tid < 128){
      atomicAdd(&slot[tid], sred[tid]);
      atomicAdd(&slot[128+tid], sred[128+tid]);
    }
  }
}

// ---------------- QKV GEMM with fused bf16/transpose epilogue ----------------
// grid (256, 3): y=0 -> Qb (scaled), y=1 -> Kb, y=2 -> VT
__global__ __launch_bounds__(256) void k_gemmqkv(const float* __restrict__ A,
    const float* __restrict__ W, const float* __restrict__ bias,
    unsigned short* __restrict__ Qb, unsigned short* __restrict__ Kb,
    unsigned short* __restrict__ VT){
  __shared__ uint4 Asm[128*4];
  __shared__ uint4 Wsm[128*4];
  __shared__ unsigned short Sm[128*136];
  int tid = threadIdx.x;
  int w = tid>>6, l = tid&63;
  int q = l&15, g = l>>4;
  int which = blockIdx.y;
  int m0 = blockIdx.x*128, n0 = which*128;
  int wr = (w>>1)*64, wc = (w&1)*64;
  const int K = 128;
  f4v acc[4][4];
  #pragma unroll
  for (int i=0;i<4;i++)
    #pragma unroll
    for (int j=0;j<4;j++) acc[i][j] = (f4v){0.f,0.f,0.f,0.f};
  int srow = tid & 127;
  int sgh  = tid >> 7;
  int sswz = (srow>>1)&3;
  for (int kc=0; kc<K; kc+=32){
    const float* pa = &A[(size_t)(m0+srow)*K + kc + sgh*16];
    float4 v0=ld4(pa), v1=ld4(pa+4), v2=ld4(pa+8), v3=ld4(pa+12);
    uint4 ca, cb;
    ca.x=pk2(v0.x,v0.y); ca.y=pk2(v0.z,v0.w); ca.z=pk2(v1.x,v1.y); ca.w=pk2(v1.z,v1.w);
    cb.x=pk2(v2.x,v2.y); cb.y=pk2(v2.z,v2.w); cb.z=pk2(v3.x,v3.y); cb.w=pk2(v3.z,v3.w);
    const float* pw = &W[(size_t)(n0+srow)*K + kc + sgh*16];
    float4 w0=ld4(pw), w1=ld4(pw+4), w2=ld4(pw+8), w3=ld4(pw+12);
    uint4 da, db;
    da.x=pk2(w0.x,w0.y); da.y=pk2(w0.z,w0.w); da.z=pk2(w1.x,w1.y); da.w=pk2(w1.z,w1.w);
    db.x=pk2(w2.x,w2.y); db.y=pk2(w2.z,w2.w); db.z=pk2(w3.x,w3.y); db.w=pk2(w3.z,w3.w);
    __syncthreads();
    Asm[srow*4 + ((2*sgh  )^sswz)] = ca;
    Asm[srow*4 + ((2*sgh+1)^sswz)] = cb;
    Wsm[srow*4 + ((2*sgh  )^sswz)] = da;
    Wsm[srow*4 + ((2*sgh+1)^sswz)] = db;
    __syncthreads();
    bf8v af[4], bfv[4];
    #pragma unroll
    for (int mt=0;mt<4;mt++){
      int R = wr + 16*mt + q;
      af[mt] = *(const bf8v*)&Asm[R*4 + (g ^ ((R>>1)&3))];
    }
    #pragma unroll
    for (int nt=0;nt<4;nt++){
      int R = wc + 16*nt + q;
      bfv[nt] = *(const bf8v*)&Wsm[R*4 + (g ^ ((R>>1)&3))];
    }
    #pragma unroll
    for (int mt=0;mt<4;mt++)
      #pragma unroll
      for (int nt=0;nt<4;nt++)
        acc[mt][nt] = __builtin_amdgcn_mfma_f32_16x16x32_bf16(af[mt], bfv[nt], acc[mt][nt], 0,0,0);
  }
  const float QSC = 0.17677669529663687f * 1.4426950408889634f;
  float scale = (which==0) ? QSC : 1.0f;
  float bbv[4];
  #pragma unroll
  for (int nt=0;nt<4;nt++) bbv[nt] = bias[n0 + wc + 16*nt + q];
  __syncthreads();
  if (which < 2){
    // row-major Sm[row][col]
    #pragma unroll
    for (int mt=0;mt<4;mt++){
      int row0 = wr + 16*mt + 4*g;
      #pragma unroll
      for (int nt=0;nt<4;nt++){
        int col = wc + 16*nt + q;
        #pragma unroll
        for (int r=0;r<4;r++)
          Sm[(row0+r)*136 + col] = bf16rn((acc[mt][nt][r] + bbv[nt]) * scale);
      }
    }
    __syncthreads();
    unsigned short* dst = (which==0) ? Qb : Kb;
    #pragma unroll
    for (int it=0; it<8; it++){
      int idx = tid + it*256;
      int row = idx >> 4, c8 = (idx & 15) * 8;
      uint4 v = *(const uint4*)&Sm[row*136 + c8];
      *(uint4*)&dst[(size_t)(m0+row)*128 + c8] = v;
    }
  } else {
    // col-major Sm[col][row]; VT[(g*128 + col)*1024 + node_local]
    #pragma unroll
    for (int mt=0;mt<4;mt++){
      int row0 = wr + 16*mt + 4*g;
      #pragma unroll
      for (int nt=0;nt<4;nt++){
        int col = wc + 16*nt + q;
        uint2 p;
        p.x = pk2(acc[mt][nt][0] + bbv[nt], acc[mt][nt][1] + bbv[nt]);
        p.y = pk2(acc[mt][nt][2] + bbv[nt], acc[mt][nt][3] + bbv[nt]);
        *(uint2*)&Sm[col*136 + row0] = p;
      }
    }
    __syncthreads();
    int gg = m0 >> 10;             // graph id
    int nl0 = m0 - gg*1024;        // node_local base
    #pragma unroll
    for (int it=0; it<8; it++){
      int idx = tid + it*256;
      int c = idx >> 4, n8 = (idx & 15) * 8;
      uint4 v = *(const uint4*)&Sm[c*136 + n8];
      *(uint4*)&VT[((size_t)gg*128 + c)*1024 + nl0 + n8] = v;
    }
  }
}

// ---------------- BatchNorm finalize + apply ----------------
__global__ __launch_bounds__(128) void k_bnfinal(const float* __restrict__ g, const float* __restrict__ b,
                                                 float* __restrict__ slot){
  int f = threadIdx.x;
  const float invn = 1.0f/32768.0f;
  float mean = slot[f]*invn;
  float var  = slot[128+f]*invn - mean*mean;
  float sc = g[f] * rsqrtf(var + 1e-5f);
  slot[256+f] = sc;
  slot[384+f] = b[f] - mean*sc;
}

template<bool RELU>
__global__ __launch_bounds__(256) void k_bnapply(const float* __restrict__ X,
                                                 const float* __restrict__ slot,
                                                 float* __restrict__ Y){
  size_t i = (size_t)blockIdx.x*256 + threadIdx.x;
  int c = (int)(i & 31) * 4;
  float4 v = ((const float4*)X)[i];
  float4 sc = *(const float4*)&slot[256+c];
  float4 sh = *(const float4*)&slot[384+c];
  float4 y;
  y.x = v.x*sc.x + sh.x; y.y = v.y*sc.y + sh.y;
  y.z = v.z*sc.z + sh.z; y.w = v.w*sc.w + sh.w;
  if (RELU){
    y.x=fmaxf(y.x,0.f); y.y=fmaxf(y.y,0.f); y.z=fmaxf(y.z,0.f); y.w=fmaxf(y.w,0.f);
  }
  ((float4*)Y)[i] = y;
}

__global__ __launch_bounds__(256) void k_add2bn(const float* __restrict__ A, const float* __restrict__ s1,
                                                const float* __restrict__ B, const float* __restrict__ s2,
                                                float* __restrict__ C){
  size_t i = (size_t)blockIdx.x*256 + threadIdx.x;
  int c = (int)(i & 31) * 4;
  float4 a = ((const float4*)A)[i];
  float4 b = ((const float4*)B)[i];
  float4 c1 = *(const float4*)&s1[256+c], d1 = *(const float4*)&s1[384+c];
  float4 c2 = *(const float4*)&s2[256+c], d2 = *(const float4*)&s2[384+c];
  float4 y;
  y.x = a.x*c1.x+d1.x + b.x*c2.x+d2.x;
  y.y = a.y*c1.y+d1.y + b.y*c2.y+d2.y;
  y.z = a.z*c1.z+d1.z + b.z*c2.z+d2.z;
  y.w = a.w*c1.w+d1.w + b.w*c2.w+d2.w;
  ((float4*)C)[i] = y;
}

// ---------------- MFMA flash attention ----------------
__global__ __launch_bounds__(256) void k_flash2(const unsigned short* __restrict__ Qb,
    const unsigned short* __restrict__ Kb, const unsigned short* __restrict__ VT,
    float* __restrict__ O){
  __shared__ unsigned short Pl[4][16*72];
  int tid = threadIdx.x;
  int w = tid >> 6, l = tid & 63;
  int q = l & 15, grp = l >> 4;
  int qt = blockIdx.x, h = blockIdx.y, g = blockIdx.z;
  size_t gbase = (size_t)g*1024;
  size_t qrow0 = gbase + qt*64 + w*16;
  const unsigned short* Vp = VT + ((size_t)(g*4 + h)*32)*1024;
  bf8v qf = *(const bf8v*)&Qb[(qrow0 + q)*128 + h*32 + 8*grp];
  unsigned short* Pw = &Pl[w][0];
  float m = -1e30f, lsum = 0.f;
  f4v o0 = {0.f,0.f,0.f,0.f}, o1 = {0.f,0.f,0.f,0.f};
  for (int kt=0; kt<16; kt++){
    int k0 = kt*64;
    f4v st[4];
    #pragma unroll
    for (int t=0;t<4;t++){
      bf8v kf = *(const bf8v*)&Kb[(gbase + k0 + 16*t + q)*128 + h*32 + 8*grp];
      st[t] = __builtin_amdgcn_mfma_f32_16x16x32_bf16(kf, qf, (f4v){0.f,0.f,0.f,0.f}, 0,0,0);
    }
    float smax = st[0][0];
    #pragma unroll
    for (int t=0;t<4;t++)
      #pragma unroll
      for (int r=0;r<4;r++) smax = fmaxf(smax, st[t][r]);
    smax = fmaxf(smax, __shfl_xor(smax, 16));
    smax = fmaxf(smax, __shfl_xor(smax, 32));
    float mnew = fmaxf(m, smax);
    float alpha = exp2f(m - mnew);
    float psum = 0.f;
    #pragma unroll
    for (int t=0;t<4;t++){
      float p0 = exp2f(st[t][0]-mnew), p1 = exp2f(st[t][1]-mnew);
      float p2 = exp2f(st[t][2]-mnew), p3 = exp2f(st[t][3]-mnew);
      psum += (p0+p1)+(p2+p3);
      *(unsigned*)&Pw[q*72 + 16*t + 4*grp]     = pk2(p0,p1);
      *(unsigned*)&Pw[q*72 + 16*t + 4*grp + 2] = pk2(p2,p3);
    }
    psum += __shfl_xor(psum, 16);
    psum += __shfl_xor(psum, 32);
    lsum = lsum*alpha + psum;
    m = mnew;
    f4v aD;
    #pragma unroll
    for (int r=0;r<4;r++) aD[r] = __shfl(alpha, 4*grp + r);
    #pragma unroll
    for (int r=0;r<4;r++){ o0[r] *= aD[r]; o1[r] *= aD[r]; }
    bf8v pa0 = *(const bf8v*)&Pw[q*72 + 8*grp];
    bf8v pa1 = *(const bf8v*)&Pw[q*72 + 32 + 8*grp];
    bf8v v00 = *(const bf8v*)&Vp[(size_t)q*1024      + k0 + 8*grp];
    bf8v v01 = *(const bf8v*)&Vp[(size_t)q*1024      + k0 + 32 + 8*grp];
    bf8v v10 = *(const bf8v*)&Vp[(size_t)(16+q)*1024 + k0 + 8*grp];
    bf8v v11 = *(const bf8v*)&Vp[(size_t)(16+q)*1024 + k0 + 32 + 8*grp];
    o0 = __builtin_amdgcn_mfma_f32_16x16x32_bf16(pa0, v00, o0, 0,0,0);
    o0 = __builtin_amdgcn_mfma_f32_16x16x32_bf16(pa1, v01, o0, 0,0,0);
    o1 = __builtin_amdgcn_mfma_f32_16x16x32_bf16(pa0, v10, o1, 0,0,0);
    o1 = __builtin_amdgcn_mfma_f32_16x16x32_bf16(pa1, v11, o1, 0,0,0);
  }
  f4v lD;
  #pragma unroll
  for (int r=0;r<4;r++) lD[r] = __shfl(lsum, 4*grp + r);
  #pragma unroll
  for (int r=0;r<4;r++){
    float inv = 1.0f/lD[r];
    size_t row = qrow0 + 4*grp + r;
    O[row*HDIM + h*32 + q]      = o0[r]*inv;
    O[row*HDIM + h*32 + 16 + q] = o1[r]*inv;
  }
}

// ---------------- host ----------------
extern "C" void kernel_launch(void* const* d_in, const int* in_sizes, int n_in,
                              void* d_out, int out_size, void* d_ws, size_t ws_size,
                              hipStream_t stream){
  const float* x_in      = (const float*)d_in[0];
  const float* edge_attr = (const float*)d_in[1];
  const float* gine_w1   = (const float*)d_in[2];
  const float* gine_b1   = (const float*)d_in[3];
  const float* gine_bn_g = (const float*)d_in[4];
  const float* gine_bn_b = (const float*)d_in[5];
  const float* gine_w2   = (const float*)d_in[6];
  const float* gine_b2   = (const float*)d_in[7];
  const float* attn_wqkv = (const float*)d_in[8];
  const float* attn_bqkv = (const float*)d_in[9];
  const float* attn_wo   = (const float*)d_in[10];
  const float* attn_bo   = (const float*)d_in[11];
  const float* norm1_g   = (const float*)d_in[12];
  const float* norm1_b   = (const float*)d_in[13];
  const float* norm2_g   = (const float*)d_in[14];
  const float* norm2_b   = (const float*)d_in[15];
  const float* norm3_g   = (const float*)d_in[16];
  const float* norm3_b   = (const float*)d_in[17];
  const float* mlp_w1    = (const float*)d_in[18];
  const float* mlp_b1    = (const float*)d_in[19];
  const float* mlp_w2    = (const float*)d_in[20];
  const float* mlp_b2    = (const float*)d_in[21];
  const int* edge_index  = (const int*)d_in[22];
  const int* srcp = edge_index;
  const int* dstp = edge_index + NE;
  float* out = (float*)d_out;

  float* ws = (float*)d_ws;
  const size_t U = 4194304; // NTOT*HDIM floats (16 MB)
  float* X     = ws;
  float* AGGR  = ws + 1*U;
  float* H1    = ws + 2*U;   // gine hidden / flash O
  float* H2    = ws + 3*U;   // attn pre-norm / mlp2 out
  float* OUT   = ws + 4*U;   // h_local + h_attn
  float* FF    = ws + 5*U;   // 2 units (NTOT x 256)
  unsigned short* Qb  = (unsigned short*)(ws + 7*U);
  unsigned short* Kb  = Qb + (size_t)NTOT*128;
  unsigned short* VTb = Kb + (size_t)NTOT*128;   // 8 MB
  float* STATS = ws + 10*U;  // 12 slots x 512 floats
  int* IW      = (int*)(STATS + 12*512);
  int* deg     = IW;
  int* indptr  = IW + 32768;
  int* cursor  = IW + 32768 + 32772;
  int* perm    = cursor + 32768;
  unsigned short* EAb = (unsigned short*)(ws + 13*U);  // NE x 128 bf16 = 134 MB (8 U)
  int* SRCp    = (int*)(ws + 21*U + U/2);              // NE ints

  hipMemsetAsync(STATS, 0, 12*512*sizeof(float), stream);
  hipMemsetAsync(deg, 0, NTOT*sizeof(int), stream);
  k_count<<<NE/256, 256, 0, stream>>>(dstp, deg);
  k_scan<<<1, 1024, 0, stream>>>(deg, indptr, cursor);
  k_fill<<<NE/256, 256, 0, stream>>>(dstp, cursor, perm);
  k_eaprep<<<NE/8, 256, 0, stream>>>(edge_attr, srcp, perm, EAb, SRCp);
  hipMemcpyAsync(X, x_in, (size_t)NTOT*HDIM*sizeof(float), hipMemcpyDeviceToDevice, stream);

  const int GAPPLY = (NTOT*HDIM/4)/256;
  dim3 gemmg1(NTOT/128, 1), gemmg2(NTOT/128, 2), gemmqkvg(NTOT/128, 3);

  for (int i=0;i<3;i++){
    const float* W1 = gine_w1 + (size_t)i*HDIM*HDIM;
    const float* B1 = gine_b1 + (size_t)i*HDIM;
    const float* W2 = gine_w2 + (size_t)i*HDIM*HDIM;
    const float* B2 = gine_b2 + (size_t)i*HDIM;
    const float* WQ = attn_wqkv + (size_t)i*3*HDIM*HDIM;
    const float* BQ = attn_bqkv + (size_t)i*3*HDIM;
    const float* WO = attn_wo + (size_t)i*HDIM*HDIM;
    const float* BO = attn_bo + (size_t)i*HDIM;
    const float* WM1 = mlp_w1 + (size_t)i*2*HDIM*HDIM;
    const float* BM1 = mlp_b1 + (size_t)i*2*HDIM;
    const float* WM2 = mlp_w2 + (size_t)i*2*HDIM*HDIM;
    const float* BM2 = mlp_b2 + (size_t)i*HDIM;
    float* S0 = STATS + (size_t)(i*4+0)*512;
    float* S1 = STATS + (size_t)(i*4+1)*512;
    float* S2 = STATS + (size_t)(i*4+2)*512;
    float* S3 = STATS + (size_t)(i*4+3)*512;

    // ---- GINE
    k_aggr<<<NTOT/8, 256, 0, stream>>>(X, EAb, SRCp, indptr, AGGR);
    k_gemm16<true,false,false,false,true><<<gemmg1, 256, 0, stream>>>(X, AGGR, nullptr, W1, B1, nullptr, H1, S0, 128, 128);
    k_bnfinal<<<1, 128, 0, stream>>>(gine_bn_g + (size_t)i*HDIM, gine_bn_b + (size_t)i*HDIM, S0);
    k_gemm16<false,true,false,true,true><<<gemmg1, 256, 0, stream>>>(H1, nullptr, S0, W2, B2, X, AGGR, S1, 128, 128);
    k_bnfinal<<<1, 128, 0, stream>>>(norm1_g + (size_t)i*HDIM, norm1_b + (size_t)i*HDIM, S1);

    // ---- attention
    k_gemmqkv<<<gemmqkvg, 256, 0, stream>>>(X, WQ, BQ, Qb, Kb, VTb);
    k_flash2<<<dim3(16, NHEAD, NGRAPH), 256, 0, stream>>>(Qb, Kb, VTb, H1);
    k_gemm16<false,false,false,true,true><<<gemmg1, 256, 0, stream>>>(H1, nullptr, nullptr, WO, BO, X, H2, S2, 128, 128);
    k_bnfinal<<<1, 128, 0, stream>>>(norm2_g + (size_t)i*HDIM, norm2_b + (size_t)i*HDIM, S2);

    // ---- combine + FFN
    k_add2bn<<<GAPPLY, 256, 0, stream>>>(AGGR, S1, H2, S2, OUT);
    k_gemm16<false,false,true,false,false><<<gemmg2, 256, 0, stream>>>(OUT, nullptr, nullptr, WM1, BM1, nullptr, FF, nullptr, 256, 128);
    k_gemm16<false,false,false,true,true><<<gemmg1, 256, 0, stream>>>(FF, nullptr, nullptr, WM2, BM2, OUT, H2, S3, 128, 256);
    k_bnfinal<<<1, 128, 0, stream>>>(norm3_g + (size_t)i*HDIM, norm3_b + (size_t)i*HDIM, S3);
    float* dest = (i==2) ? out : X;
    if (i<2) k_bnapply<true ><<<GAPPLY, 256, 0, stream>>>(H2, S3, dest);
    else     k_bnapply<false><<<GAPPLY, 256, 0, stream>>>(H2, S3, dest);
  }
}

// Round 5
// 1048.961 us; speedup vs baseline: 2.0829x; 1.1074x over previous
//
#include <hip/hip_runtime.h>
#include <hip/hip_bf16.h>
#include <math.h>

#define NTOT 32768
#define HDIM 128
#define NE   524288
#define NGRAPH 32
#define NNODE 1024
#define NHEAD 4
#define DHEAD 32

typedef __attribute__((ext_vector_type(8))) short bf8v;
typedef __attribute__((ext_vector_type(4))) float f4v;
typedef unsigned short u16;

__device__ __forceinline__ float4 ld4(const float* p){ return *(const float4*)p; }

__device__ __forceinline__ u16 bf16rn(float f){
  union { float f; unsigned u; } x; x.f = f;
  unsigned r = x.u + 0x7FFF + ((x.u >> 16) & 1);
  return (u16)(r >> 16);
}
__device__ __forceinline__ unsigned pk2(float a, float b){
  unsigned r;
  asm("v_cvt_pk_bf16_f32 %0, %1, %2" : "=v"(r) : "v"(a), "v"(b));
  return r;
}
__device__ __forceinline__ float bf2f(u16 u){
  union { unsigned u; float f; } x; x.u = ((unsigned)u) << 16;
  return x.f;
}

// ---------------- CSR build ----------------
__global__ void k_count(const int* __restrict__ dst, int* __restrict__ deg){
  int e = blockIdx.x*256 + threadIdx.x;
  atomicAdd(&deg[dst[e]], 1);
}

__global__ __launch_bounds__(1024) void k_scan(const int* __restrict__ deg,
                                               int* __restrict__ indptr,
                                               int* __restrict__ cursor){
  __shared__ int sm[1024];
  int t = threadIdx.x;
  int base = t*32;
  int s = 0;
  for (int j=0;j<32;j++) s += deg[base+j];
  sm[t] = s; __syncthreads();
  for (int off=1; off<1024; off<<=1){
    int v = (t>=off) ? sm[t-off] : 0;
    __syncthreads();
    sm[t] += v;
    __syncthreads();
  }
  int ex = sm[t] - s;
  for (int j=0;j<32;j++){
    int d = deg[base+j];
    indptr[base+j] = ex; cursor[base+j] = ex;
    ex += d;
  }
  if (t == 1023) indptr[NTOT] = ex;
}

__global__ void k_fill(const int* __restrict__ dst, int* __restrict__ cursor,
                       int* __restrict__ perm){
  int e = blockIdx.x*256 + threadIdx.x;
  int pos = atomicAdd(&cursor[dst[e]], 1);
  perm[pos] = e;
}

// one-time: permute edge_attr into CSR order as bf16; permute src too
__global__ __launch_bounds__(256) void k_eaprep(const float* __restrict__ ea,
    const int* __restrict__ src, const int* __restrict__ perm,
    u16* __restrict__ EAb, int* __restrict__ SRCp){
  int tid = threadIdx.x;
  int p = blockIdx.x*8 + (tid>>5);
  int c4 = (tid&31)*4;
  int e = perm[p];
  float4 v = ld4(&ea[(size_t)e*HDIM + c4]);
  uint2 o; o.x = pk2(v.x, v.y); o.y = pk2(v.z, v.w);
  *(uint2*)&EAb[(size_t)p*HDIM + c4] = o;
  if ((tid&31) == 0) SRCp[p] = src[e];
}

// one-time: x fp32 -> bf16
__global__ __launch_bounds__(256) void k_xprep(const float* __restrict__ x, u16* __restrict__ Xb){
  size_t i = ((size_t)blockIdx.x*256 + threadIdx.x)*4;
  float4 v = ld4(&x[i]);
  uint2 o; o.x = pk2(v.x,v.y); o.y = pk2(v.z,v.w);
  *(uint2*)&Xb[i] = o;
}

// one-time: all weights fp32 -> bf16 (6 sources via blockIdx.y)
__global__ __launch_bounds__(256) void k_wprep(const float* s0,const float* s1,const float* s2,
    const float* s3,const float* s4,const float* s5, u16* __restrict__ Wb){
  const float* srcs[6] = {s0,s1,s2,s3,s4,s5};
  const int cnt4[6] = {12288,12288,36864,12288,24576,24576};
  const int off[6]  = {0,49152,98304,245760,294912,393216};
  int y = blockIdx.y;
  int i = blockIdx.x*256 + threadIdx.x;
  if (i >= cnt4[y]) return;
  float4 v = ld4(&srcs[y][(size_t)i*4]);
  uint2 o; o.x = pk2(v.x,v.y); o.y = pk2(v.z,v.w);
  *(uint2*)&Wb[off[y] + (size_t)i*4] = o;
}

// Hb[n][:] = Xb[n] + sum over CSR edges of relu(Xb[src] + ea)
__global__ __launch_bounds__(256) void k_aggr(const u16* __restrict__ Xb,
                       const u16* __restrict__ EAb,
                       const int* __restrict__ SRCp, const int* __restrict__ indptr,
                       u16* __restrict__ Hb){
  int tid = threadIdx.x;
  int n = blockIdx.x*8 + (tid>>5);
  int c4 = (tid&31)*4;
  int p0 = indptr[n], p1 = indptr[n+1];
  float a0=0.f,a1=0.f,a2=0.f,a3=0.f;
  for (int p=p0;p<p1;p++){
    int s = SRCp[p];
    uint2 xv = *(const uint2*)&Xb[(size_t)s*HDIM + c4];
    uint2 ev = *(const uint2*)&EAb[(size_t)p*HDIM + c4];
    a0 += fmaxf(bf2f((u16)(xv.x&0xffff)) + bf2f((u16)(ev.x&0xffff)), 0.f);
    a1 += fmaxf(bf2f((u16)(xv.x>>16))    + bf2f((u16)(ev.x>>16)), 0.f);
    a2 += fmaxf(bf2f((u16)(xv.y&0xffff)) + bf2f((u16)(ev.y&0xffff)), 0.f);
    a3 += fmaxf(bf2f((u16)(xv.y>>16))    + bf2f((u16)(ev.y>>16)), 0.f);
  }
  uint2 xn = *(const uint2*)&Xb[(size_t)n*HDIM + c4];
  a0 += bf2f((u16)(xn.x&0xffff)); a1 += bf2f((u16)(xn.x>>16));
  a2 += bf2f((u16)(xn.y&0xffff)); a3 += bf2f((u16)(xn.y>>16));
  uint2 o; o.x = pk2(a0,a1); o.y = pk2(a2,a3);
  *(uint2*)&Hb[(size_t)n*HDIM + c4] = o;
}

// ---------------- LDS-free bf16 MFMA GEMM ----------------
// BM=128, BN=64, 256 thr = 4 waves x 32 rows. C = act(stageA @ W^T + bias (+Ep))
// stageA: plain | relu(bn(A,slotA)) | bn(A,slotA)+bn(A2,slotB) (dual, side-write OUT)
template<bool BNA, bool DUAL, bool RELU, bool EP, bool STATS, bool WROUT>
__global__ __launch_bounds__(256) void k_bgemm(const u16* __restrict__ Ab,
    const u16* __restrict__ A2b,
    const float* __restrict__ slotA, const float* __restrict__ gA, const float* __restrict__ bA,
    const float* __restrict__ slotB, const float* __restrict__ gB, const float* __restrict__ bB,
    const u16* __restrict__ Wb, const float* __restrict__ bias,
    const u16* __restrict__ Epb, u16* __restrict__ Cb,
    u16* __restrict__ OUTb, float* __restrict__ slotOut, int N, int K){
  __shared__ float sbnA[256];
  __shared__ float sbnB[256];
  __shared__ float sred[128];
  int tid = threadIdx.x;
  int w = tid>>6, l = tid&63;
  int q = l&15, g = l>>4;
  int m0 = blockIdx.x*128, n0 = blockIdx.y*64;
  int wr = w*32;
  const float invn = 1.0f/32768.0f;
  if (BNA || DUAL){
    if (tid < 128){
      float mean = slotA[tid]*invn;
      float var  = slotA[128+tid]*invn - mean*mean;
      float sc = gA[tid] * rsqrtf(var + 1e-5f);
      sbnA[tid] = sc; sbnA[128+tid] = bA[tid] - mean*sc;
      if (DUAL){
        float mean2 = slotB[tid]*invn;
        float var2  = slotB[128+tid]*invn - mean2*mean2;
        float sc2 = gB[tid] * rsqrtf(var2 + 1e-5f);
        sbnB[tid] = sc2; sbnB[128+tid] = bB[tid] - mean2*sc2;
      }
    }
  }
  if (STATS && tid < 128) sred[tid] = 0.f;
  if (BNA || DUAL || STATS) __syncthreads();

  f4v acc[2][4];
  #pragma unroll
  for (int i=0;i<2;i++)
    #pragma unroll
    for (int j=0;j<4;j++) acc[i][j] = (f4v){0.f,0.f,0.f,0.f};

  for (int kc=0; kc<K; kc+=32){
    bf8v af[2], bfv[4];
    #pragma unroll
    for (int mt=0;mt<2;mt++){
      int row = m0 + wr + 16*mt + q;
      if (!BNA && !DUAL){
        af[mt] = *(const bf8v*)&Ab[(size_t)row*K + kc + 8*g];
      } else {
        union { bf8v b; u16 s[8]; unsigned u[4]; } ra, r2, ro;
        ra.b = *(const bf8v*)&Ab[(size_t)row*K + kc + 8*g];
        if (DUAL) r2.b = *(const bf8v*)&A2b[(size_t)row*K + kc + 8*g];
        float v[8];
        #pragma unroll
        for (int j=0;j<8;j++){
          int kk = kc + 8*g + j;
          float f = bf2f(ra.s[j]) * sbnA[kk] + sbnA[128+kk];
          if (BNA) f = fmaxf(f, 0.f);
          if (DUAL) f += bf2f(r2.s[j]) * sbnB[kk] + sbnB[128+kk];
          v[j] = f;
        }
        ro.u[0]=pk2(v[0],v[1]); ro.u[1]=pk2(v[2],v[3]);
        ro.u[2]=pk2(v[4],v[5]); ro.u[3]=pk2(v[6],v[7]);
        af[mt] = ro.b;
        if (WROUT && blockIdx.y == 0)
          *(uint4*)&OUTb[(size_t)row*K + kc + 8*g] = *(uint4*)ro.u;
      }
    }
    #pragma unroll
    for (int nt=0;nt<4;nt++){
      int col = n0 + 16*nt + q;
      bfv[nt] = *(const bf8v*)&Wb[(size_t)col*K + kc + 8*g];
    }
    #pragma unroll
    for (int mt=0;mt<2;mt++)
      #pragma unroll
      for (int nt=0;nt<4;nt++)
        acc[mt][nt] = __builtin_amdgcn_mfma_f32_16x16x32_bf16(af[mt], bfv[nt], acc[mt][nt], 0,0,0);
  }
  float bbv[4];
  #pragma unroll
  for (int nt=0;nt<4;nt++) bbv[nt] = bias[n0 + 16*nt + q];
  float csum[4] = {0.f,0.f,0.f,0.f}, csq[4] = {0.f,0.f,0.f,0.f};
  #pragma unroll
  for (int mt=0;mt<2;mt++){
    int row0 = m0 + wr + 16*mt + 4*g;
    #pragma unroll
    for (int nt=0;nt<4;nt++){
      int col = n0 + 16*nt + q;
      #pragma unroll
      for (int r=0;r<4;r++){
        size_t off = (size_t)(row0+r)*N + col;
        float v = acc[mt][nt][r] + bbv[nt];
        if (EP) v += bf2f(Epb[off]);
        if (RELU) v = fmaxf(v, 0.f);
        Cb[off] = bf16rn(v);
        if (STATS){ csum[nt] += v; csq[nt] += v*v; }
      }
    }
  }
  if (STATS){
    #pragma unroll
    for (int nt=0;nt<4;nt++){
      int c = 16*nt + q;
      atomicAdd(&sred[c], csum[nt]);
      atomicAdd(&sred[64+c], csq[nt]);
    }
    __syncthreads();
    if (tid < 64){
      atomicAdd(&slotOut[n0+tid], sred[tid]);
      atomicAdd(&slotOut[128+n0+tid], sred[64+tid]);
    }
  }
}

// ---------------- QKV GEMM, LDS-free mainloop + transpose epilogues ----------------
// grid (256, 6): by -> 64-col chunk of [Q0 Q1 K0 K1 V0 V1]
__global__ __launch_bounds__(256) void k_qkvgemm(const u16* __restrict__ Ab,
    const u16* __restrict__ Wb, const float* __restrict__ bias,
    u16* __restrict__ Qb, u16* __restrict__ Kb, u16* __restrict__ VT){
  __shared__ u16 Sm[128*72];
  int tid = threadIdx.x;
  int w = tid>>6, l = tid&63;
  int q = l&15, g = l>>4;
  int m0 = blockIdx.x*128, n0 = blockIdx.y*64;
  int which = blockIdx.y >> 1, half = blockIdx.y & 1;
  int wr = w*32;
  const int K = 128;
  f4v acc[2][4];
  #pragma unroll
  for (int i=0;i<2;i++)
    #pragma unroll
    for (int j=0;j<4;j++) acc[i][j] = (f4v){0.f,0.f,0.f,0.f};
  for (int kc=0; kc<K; kc+=32){
    bf8v af[2], bfv[4];
    #pragma unroll
    for (int mt=0;mt<2;mt++)
      af[mt] = *(const bf8v*)&Ab[(size_t)(m0+wr+16*mt+q)*K + kc + 8*g];
    #pragma unroll
    for (int nt=0;nt<4;nt++)
      bfv[nt] = *(const bf8v*)&Wb[(size_t)(n0+16*nt+q)*K + kc + 8*g];
    #pragma unroll
    for (int mt=0;mt<2;mt++)
      #pragma unroll
      for (int nt=0;nt<4;nt++)
        acc[mt][nt] = __builtin_amdgcn_mfma_f32_16x16x32_bf16(af[mt], bfv[nt], acc[mt][nt], 0,0,0);
  }
  const float QSC = 0.17677669529663687f * 1.4426950408889634f;
  float scale = (which==0) ? QSC : 1.0f;
  float bbv[4];
  #pragma unroll
  for (int nt=0;nt<4;nt++) bbv[nt] = bias[n0 + 16*nt + q];
  if (which < 2){
    // row-major Sm[row][64] (pad 72)
    #pragma unroll
    for (int mt=0;mt<2;mt++){
      int row0 = wr + 16*mt + 4*g;
      #pragma unroll
      for (int nt=0;nt<4;nt++){
        int c = 16*nt + q;
        #pragma unroll
        for (int r=0;r<4;r++)
          Sm[(row0+r)*72 + c] = bf16rn((acc[mt][nt][r] + bbv[nt]) * scale);
      }
    }
    __syncthreads();
    u16* dst = (which==0) ? Qb : Kb;
    #pragma unroll
    for (int it=0; it<4; it++){
      int idx = tid + it*256;
      int row = idx >> 3, c8 = (idx & 7) * 8;
      uint4 v = *(const uint4*)&Sm[row*72 + c8];
      *(uint4*)&dst[(size_t)(m0+row)*128 + half*64 + c8] = v;
    }
  } else {
    // col-major Sm[col][128] (stride 136)
    #pragma unroll
    for (int mt=0;mt<2;mt++){
      int row0 = wr + 16*mt + 4*g;
      #pragma unroll
      for (int nt=0;nt<4;nt++){
        int c = 16*nt + q;
        uint2 p;
        p.x = pk2(acc[mt][nt][0] + bbv[nt], acc[mt][nt][1] + bbv[nt]);
        p.y = pk2(acc[mt][nt][2] + bbv[nt], acc[mt][nt][3] + bbv[nt]);
        *(uint2*)&Sm[c*136 + row0] = p;
      }
    }
    __syncthreads();
    int gg = m0 >> 10;
    int nl0 = m0 - gg*1024;
    #pragma unroll
    for (int it=0; it<4; it++){
      int idx = tid + it*256;
      int c = idx >> 4, n8 = (idx & 15) * 8;
      uint4 v = *(const uint4*)&Sm[c*136 + n8];
      *(uint4*)&VT[((size_t)gg*128 + half*64 + c)*1024 + nl0 + n8] = v;
    }
  }
}

// ---------------- BN apply (finalize inline) ----------------
template<bool RELU, bool F32OUT>
__global__ __launch_bounds__(256) void k_bnapply(const u16* __restrict__ X,
    const float* __restrict__ slot, const float* __restrict__ gv, const float* __restrict__ bv,
    u16* __restrict__ Yb, float* __restrict__ Yf){
  int idx = blockIdx.x*256 + threadIdx.x;
  int row = idx >> 4, c8 = (idx & 15) * 8;
  const float invn = 1.0f/32768.0f;
  union { uint4 u; u16 s[8]; } iv;
  iv.u = *(const uint4*)&X[(size_t)row*HDIM + c8];
  float o[8];
  #pragma unroll
  for (int j=0;j<8;j++){
    int c = c8+j;
    float mean = slot[c]*invn;
    float var  = slot[128+c]*invn - mean*mean;
    float sc = gv[c] * rsqrtf(var + 1e-5f);
    float sh = bv[c] - mean*sc;
    float v = bf2f(iv.s[j])*sc + sh;
    if (RELU) v = fmaxf(v, 0.f);
    o[j] = v;
  }
  if (F32OUT){
    float* dst = &Yf[(size_t)row*HDIM + c8];
    *(float4*)dst = make_float4(o[0],o[1],o[2],o[3]);
    *(float4*)(dst+4) = make_float4(o[4],o[5],o[6],o[7]);
  } else {
    uint4 ov;
    ov.x = pk2(o[0],o[1]); ov.y = pk2(o[2],o[3]);
    ov.z = pk2(o[4],o[5]); ov.w = pk2(o[6],o[7]);
    *(uint4*)&Yb[(size_t)row*HDIM + c8] = ov;
  }
}

// ---------------- MFMA flash attention (bf16 O out) ----------------
__global__ __launch_bounds__(256) void k_flash2(const u16* __restrict__ Qb,
    const u16* __restrict__ Kb, const u16* __restrict__ VT,
    u16* __restrict__ O){
  __shared__ u16 Pl[4][16*72];
  int tid = threadIdx.x;
  int w = tid >> 6, l = tid & 63;
  int q = l & 15, grp = l >> 4;
  int qt = blockIdx.x, h = blockIdx.y, g = blockIdx.z;
  size_t gbase = (size_t)g*1024;
  size_t qrow0 = gbase + qt*64 + w*16;
  const u16* Vp = VT + ((size_t)(g*4 + h)*32)*1024;
  bf8v qf = *(const bf8v*)&Qb[(qrow0 + q)*128 + h*32 + 8*grp];
  u16* Pw = &Pl[w][0];
  float m = -1e30f, lsum = 0.f;
  f4v o0 = {0.f,0.f,0.f,0.f}, o1 = {0.f,0.f,0.f,0.f};
  for (int kt=0; kt<16; kt++){
    int k0 = kt*64;
    f4v st[4];
    #pragma unroll
    for (int t=0;t<4;t++){
      bf8v kf = *(const bf8v*)&Kb[(gbase + k0 + 16*t + q)*128 + h*32 + 8*grp];
      st[t] = __builtin_amdgcn_mfma_f32_16x16x32_bf16(kf, qf, (f4v){0.f,0.f,0.f,0.f}, 0,0,0);
    }
    float smax = st[0][0];
    #pragma unroll
    for (int t=0;t<4;t++)
      #pragma unroll
      for (int r=0;r<4;r++) smax = fmaxf(smax, st[t][r]);
    smax = fmaxf(smax, __shfl_xor(smax, 16));
    smax = fmaxf(smax, __shfl_xor(smax, 32));
    float mnew = fmaxf(m, smax);
    float alpha = exp2f(m - mnew);
    float psum = 0.f;
    #pragma unroll
    for (int t=0;t<4;t++){
      float p0 = exp2f(st[t][0]-mnew), p1 = exp2f(st[t][1]-mnew);
      float p2 = exp2f(st[t][2]-mnew), p3 = exp2f(st[t][3]-mnew);
      psum += (p0+p1)+(p2+p3);
      *(unsigned*)&Pw[q*72 + 16*t + 4*grp]     = pk2(p0,p1);
      *(unsigned*)&Pw[q*72 + 16*t + 4*grp + 2] = pk2(p2,p3);
    }
    psum += __shfl_xor(psum, 16);
    psum += __shfl_xor(psum, 32);
    lsum = lsum*alpha + psum;
    m = mnew;
    f4v aD;
    #pragma unroll
    for (int r=0;r<4;r++) aD[r] = __shfl(alpha, 4*grp + r);
    #pragma unroll
    for (int r=0;r<4;r++){ o0[r] *= aD[r]; o1[r] *= aD[r]; }
    bf8v pa0 = *(const bf8v*)&Pw[q*72 + 8*grp];
    bf8v pa1 = *(const bf8v*)&Pw[q*72 + 32 + 8*grp];
    bf8v v00 = *(const bf8v*)&Vp[(size_t)q*1024      + k0 + 8*grp];
    bf8v v01 = *(const bf8v*)&Vp[(size_t)q*1024      + k0 + 32 + 8*grp];
    bf8v v10 = *(const bf8v*)&Vp[(size_t)(16+q)*1024 + k0 + 8*grp];
    bf8v v11 = *(const bf8v*)&Vp[(size_t)(16+q)*1024 + k0 + 32 + 8*grp];
    o0 = __builtin_amdgcn_mfma_f32_16x16x32_bf16(pa0, v00, o0, 0,0,0);
    o0 = __builtin_amdgcn_mfma_f32_16x16x32_bf16(pa1, v01, o0, 0,0,0);
    o1 = __builtin_amdgcn_mfma_f32_16x16x32_bf16(pa0, v10, o1, 0,0,0);
    o1 = __builtin_amdgcn_mfma_f32_16x16x32_bf16(pa1, v11, o1, 0,0,0);
  }
  f4v lD;
  #pragma unroll
  for (int r=0;r<4;r++) lD[r] = __shfl(lsum, 4*grp + r);
  #pragma unroll
  for (int r=0;r<4;r++){
    float inv = 1.0f/lD[r];
    size_t row = qrow0 + 4*grp + r;
    O[row*HDIM + h*32 + q]      = bf16rn(o0[r]*inv);
    O[row*HDIM + h*32 + 16 + q] = bf16rn(o1[r]*inv);
  }
}

// ---------------- host ----------------
extern "C" void kernel_launch(void* const* d_in, const int* in_sizes, int n_in,
                              void* d_out, int out_size, void* d_ws, size_t ws_size,
                              hipStream_t stream){
  const float* x_in      = (const float*)d_in[0];
  const float* edge_attr = (const float*)d_in[1];
  const float* gine_w1   = (const float*)d_in[2];
  const float* gine_b1   = (const float*)d_in[3];
  const float* gine_bn_g = (const float*)d_in[4];
  const float* gine_bn_b = (const float*)d_in[5];
  const float* gine_w2   = (const float*)d_in[6];
  const float* gine_b2   = (const float*)d_in[7];
  const float* attn_wqkv = (const float*)d_in[8];
  const float* attn_bqkv = (const float*)d_in[9];
  const float* attn_wo   = (const float*)d_in[10];
  const float* attn_bo   = (const float*)d_in[11];
  const float* norm1_g   = (const float*)d_in[12];
  const float* norm1_b   = (const float*)d_in[13];
  const float* norm2_g   = (const float*)d_in[14];
  const float* norm2_b   = (const float*)d_in[15];
  const float* norm3_g   = (const float*)d_in[16];
  const float* norm3_b   = (const float*)d_in[17];
  const float* mlp_w1    = (const float*)d_in[18];
  const float* mlp_b1    = (const float*)d_in[19];
  const float* mlp_w2    = (const float*)d_in[20];
  const float* mlp_b2    = (const float*)d_in[21];
  const int* edge_index  = (const int*)d_in[22];
  const int* srcp = edge_index;
  const int* dstp = edge_index + NE;
  float* out = (float*)d_out;

  float* ws = (float*)d_ws;
  const size_t U = 4194304;            // 16 MB in floats
  u16* Xb   = (u16*)(ws);              // 8 MB each
  u16* Hb   = (u16*)(ws + U/2);
  u16* G1   = (u16*)(ws + U);
  u16* P1   = (u16*)(ws + U + U/2);
  u16* P2   = (u16*)(ws + 2*U);
  u16* Ob   = (u16*)(ws + 2*U + U/2);
  u16* FFb  = (u16*)(ws + 3*U);        // 16 MB (NTOT x 256)
  u16* OUTb = (u16*)(ws + 4*U);
  u16* H3   = (u16*)(ws + 4*U + U/2);
  u16* Qb   = (u16*)(ws + 5*U);
  u16* Kb   = (u16*)(ws + 5*U + U/2);
  u16* VTb  = (u16*)(ws + 6*U);
  u16* Wball= (u16*)(ws + 6*U + U/2);  // 983 KB
  float* STATS = ws + 7*U - 8192;      // 12 slots x 512 floats
  int* IW      = (int*)(ws + 7*U);
  int* deg     = IW;
  int* indptr  = IW + 32768;
  int* cursor  = IW + 32768 + 32772;
  int* perm    = cursor + 32768;       // 524288 ints -> ends well before 8U
  u16* EAb  = (u16*)(ws + 8*U);        // 128 MB -> ends at 16U
  int* SRCp = (int*)(ws + 16*U);       // 2 MB

  // bf16 weight cache offsets (ushorts)
  u16* W1b  = Wball + 0;
  u16* W2b  = Wball + 49152;
  u16* WQb  = Wball + 98304;
  u16* WOb  = Wball + 245760;
  u16* WM1b = Wball + 294912;
  u16* WM2b = Wball + 393216;

  hipMemsetAsync(STATS, 0, 12*512*sizeof(float), stream);
  hipMemsetAsync(deg, 0, NTOT*sizeof(int), stream);
  k_count<<<NE/256, 256, 0, stream>>>(dstp, deg);
  k_scan<<<1, 1024, 0, stream>>>(deg, indptr, cursor);
  k_fill<<<NE/256, 256, 0, stream>>>(dstp, cursor, perm);
  k_eaprep<<<NE/8, 256, 0, stream>>>(edge_attr, srcp, perm, EAb, SRCp);
  k_xprep<<<4096, 256, 0, stream>>>(x_in, Xb);
  k_wprep<<<dim3(144,6), 256, 0, stream>>>(gine_w1, gine_w2, attn_wqkv, attn_wo, mlp_w1, mlp_w2, Wball);

  dim3 gN128(NTOT/128, 2), gN256(NTOT/128, 4), gQKV(NTOT/128, 6);

  for (int i=0;i<3;i++){
    const float* B1 = gine_b1 + (size_t)i*HDIM;
    const float* B2 = gine_b2 + (size_t)i*HDIM;
    const float* BQ = attn_bqkv + (size_t)i*3*HDIM;
    const float* BO = attn_bo + (size_t)i*HDIM;
    const float* BM1 = mlp_b1 + (size_t)i*2*HDIM;
    const float* BM2 = mlp_b2 + (size_t)i*HDIM;
    u16* w1 = W1b + (size_t)i*16384;
    u16* w2 = W2b + (size_t)i*16384;
    u16* wq = WQb + (size_t)i*49152;
    u16* wo = WOb + (size_t)i*16384;
    u16* wm1 = WM1b + (size_t)i*32768;
    u16* wm2 = WM2b + (size_t)i*32768;
    float* S0 = STATS + (size_t)(i*4+0)*512;
    float* S1 = STATS + (size_t)(i*4+1)*512;
    float* S2 = STATS + (size_t)(i*4+2)*512;
    float* S3 = STATS + (size_t)(i*4+3)*512;
    const float* bnG = gine_bn_g + (size_t)i*HDIM;
    const float* bnB = gine_bn_b + (size_t)i*HDIM;
    const float* n1g = norm1_g + (size_t)i*HDIM, *n1b = norm1_b + (size_t)i*HDIM;
    const float* n2g = norm2_g + (size_t)i*HDIM, *n2b = norm2_b + (size_t)i*HDIM;
    const float* n3g = norm3_g + (size_t)i*HDIM, *n3b = norm3_b + (size_t)i*HDIM;

    // GINE: Hb = x + aggr; G1 = Hb@W1+b1 (stats S0); P1 = relu(bn(G1,S0))@W2+b2 + x (stats S1)
    k_aggr<<<NTOT/8, 256, 0, stream>>>(Xb, EAb, SRCp, indptr, Hb);
    k_bgemm<false,false,false,false,true,false><<<gN128, 256, 0, stream>>>(
      Hb, nullptr, nullptr,nullptr,nullptr, nullptr,nullptr,nullptr,
      w1, B1, nullptr, G1, nullptr, S0, 128, 128);
    k_bgemm<true,false,false,true,true,false><<<gN128, 256, 0, stream>>>(
      G1, nullptr, S0, bnG, bnB, nullptr,nullptr,nullptr,
      w2, B2, Xb, P1, nullptr, S1, 128, 128);

    // attention: QKV -> flash -> O-proj (+x residual, stats S2)
    k_qkvgemm<<<gQKV, 256, 0, stream>>>(Xb, wq, BQ, Qb, Kb, VTb);
    k_flash2<<<dim3(16, NHEAD, NGRAPH), 256, 0, stream>>>(Qb, Kb, VTb, Ob);
    k_bgemm<false,false,false,true,true,false><<<gN128, 256, 0, stream>>>(
      Ob, nullptr, nullptr,nullptr,nullptr, nullptr,nullptr,nullptr,
      wo, BO, Xb, P2, nullptr, S2, 128, 128);

    // FFN: stage OUT = bn(P1,S1)+bn(P2,S2) (side-write), FF = relu(OUT@WM1+b)
    k_bgemm<false,true,true,false,false,true><<<gN256, 256, 0, stream>>>(
      P1, P2, S1, n1g, n1b, S2, n2g, n2b,
      wm1, BM1, nullptr, FFb, OUTb, nullptr, 256, 128);
    // H3 = FF@WM2+b + OUT (stats S3)
    k_bgemm<false,false,false,true,true,false><<<gN128, 256, 0, stream>>>(
      FFb, nullptr, nullptr,nullptr,nullptr, nullptr,nullptr,nullptr,
      wm2, BM2, OUTb, H3, nullptr, S3, 128, 256);

    if (i<2) k_bnapply<true ,false><<<2048, 256, 0, stream>>>(H3, S3, n3g, n3b, Xb, nullptr);
    else     k_bnapply<false,true ><<<2048, 256, 0, stream>>>(H3, S3, n3g, n3b, nullptr, out);
  }
}